// Round 1
// baseline (1024.338 us; speedup 1.0000x reference)
//
#include <hip/hip_runtime.h>
#include <hip/hip_bf16.h>
#include <stdint.h>

typedef __bf16 bf16;
typedef __bf16 bf16x8 __attribute__((ext_vector_type(8)));
typedef float f32x4 __attribute__((ext_vector_type(4)));
typedef unsigned int u32;

#define MFMA16(a, b, c) __builtin_amdgcn_mfma_f32_16x16x32_bf16(a, b, c, 0, 0, 0)

typedef const u32 __attribute__((address_space(1)))* gptr1;
typedef u32 __attribute__((address_space(3)))* lptr3;

__device__ __forceinline__ void load_lds16(const void* g, void* l) {
    __builtin_amdgcn_global_load_lds((gptr1)g, (lptr3)l, 16, 0, 0);
}

#define SCALE_QK 0.08838834764831845f   // 1/sqrt(128)
#define RMS_EPS 1.1920929e-07f
#define OUT_SCALE 0.2f                   // 1 - LAMBDA_INIT

// ---------------------------------------------------------------- converts
__global__ void cvt_act(const float* __restrict__ x, const float* __restrict__ enc,
                        bf16* __restrict__ xb, bf16* __restrict__ eb) {
    int gid = blockIdx.x * 256 + threadIdx.x;   // 0..262143
    const float* src = (gid < 131072) ? x : enc;
    bf16* dst = (gid < 131072) ? xb : eb;
    int i = (gid & 131071) * 8;
    float4 v0 = *(const float4*)(src + i);
    float4 v1 = *(const float4*)(src + i + 4);
    union { bf16 h[8]; uint4 u; } p;
    p.h[0] = (bf16)v0.x; p.h[1] = (bf16)v0.y; p.h[2] = (bf16)v0.z; p.h[3] = (bf16)v0.w;
    p.h[4] = (bf16)v1.x; p.h[5] = (bf16)v1.y; p.h[6] = (bf16)v1.z; p.h[7] = (bf16)v1.w;
    *(uint4*)(dst + i) = p.u;
}

// Wq/Wk/Wv (H,E,DH) f32  ->  WT (H*DH, E) bf16  (per-h 256x256 transpose)
__global__ void txp_w(const float* __restrict__ Wq, const float* __restrict__ Wk,
                      const float* __restrict__ Wv,
                      bf16* __restrict__ WTq, bf16* __restrict__ WTk, bf16* __restrict__ WTv) {
    int z = blockIdx.z; int iw = z >> 4, hh = z & 15;
    const float* src = (iw == 0 ? Wq : iw == 1 ? Wk : Wv) + hh * 65536;
    bf16* dst = (iw == 0 ? WTq : iw == 1 ? WTk : WTv) + hh * 65536;
    __shared__ bf16 T[64][68];
    int r0 = blockIdx.y * 64, c0 = blockIdx.x * 64;
    int tid = threadIdx.x;
#pragma unroll
    for (int t = 0; t < 4; ++t) {
        int idx = tid + t * 256;
        int row = idx >> 4, c4 = (idx & 15) * 4;
        float4 v = *(const float4*)(src + (r0 + row) * 256 + c0 + c4);
        T[row][c4] = (bf16)v.x; T[row][c4 + 1] = (bf16)v.y;
        T[row][c4 + 2] = (bf16)v.z; T[row][c4 + 3] = (bf16)v.w;
    }
    __syncthreads();
#pragma unroll
    for (int t = 0; t < 2; ++t) {
        int idx = tid + t * 256;
        int crow = idx >> 3, r8 = (idx & 7) * 8;
        union { bf16 h[8]; uint4 u; } p;
#pragma unroll
        for (int j = 0; j < 8; ++j) p.h[j] = T[r8 + j][crow];
        *(uint4*)(dst + (c0 + crow) * 256 + r0 + r8) = p.u;
    }
}

// Wo (D=4096, E=256) f32 -> WoT (256, 4096) bf16
__global__ void txp_wo(const float* __restrict__ Wo, bf16* __restrict__ WoT) {
    __shared__ bf16 T[64][68];
    int r0 = blockIdx.y * 64, c0 = blockIdx.x * 64;
    int tid = threadIdx.x;
#pragma unroll
    for (int t = 0; t < 4; ++t) {
        int idx = tid + t * 256;
        int row = idx >> 4, c4 = (idx & 15) * 4;
        float4 v = *(const float4*)(Wo + (size_t)(r0 + row) * 256 + c0 + c4);
        T[row][c4] = (bf16)v.x; T[row][c4 + 1] = (bf16)v.y;
        T[row][c4 + 2] = (bf16)v.z; T[row][c4 + 3] = (bf16)v.w;
    }
    __syncthreads();
#pragma unroll
    for (int t = 0; t < 2; ++t) {
        int idx = tid + t * 256;
        int crow = idx >> 3, r8 = (idx & 7) * 8;
        union { bf16 h[8]; uint4 u; } p;
#pragma unroll
        for (int j = 0; j < 8; ++j) p.h[j] = T[r8 + j][crow];
        *(uint4*)(WoT + (size_t)(c0 + crow) * 4096 + r0 + r8) = p.u;
    }
}

// V [bh][2048][256] bf16 -> VT [bh][256][2048] bf16
__global__ void txp_v(const bf16* __restrict__ V, bf16* __restrict__ VT) {
    int bh = blockIdx.z;
    const bf16* src = V + (size_t)bh * 2048 * 256;
    bf16* dst = VT + (size_t)bh * 256 * 2048;
    __shared__ bf16 T[64][68];
    int s0 = blockIdx.x * 64, d0 = blockIdx.y * 64;
    int tid = threadIdx.x;
#pragma unroll
    for (int t = 0; t < 2; ++t) {
        int idx = tid + t * 256;
        int row = idx >> 3, c8 = (idx & 7) * 8;
        uint4 v = *(const uint4*)(src + (s0 + row) * 256 + d0 + c8);
        *(uint2*)&T[row][c8] = make_uint2(v.x, v.y);
        *(uint2*)&T[row][c8 + 4] = make_uint2(v.z, v.w);
    }
    __syncthreads();
#pragma unroll
    for (int t = 0; t < 2; ++t) {
        int idx = tid + t * 256;
        int crow = idx >> 3, r8 = (idx & 7) * 8;
        union { bf16 h[8]; uint4 u; } p;
#pragma unroll
        for (int j = 0; j < 8; ++j) p.h[j] = T[r8 + j][crow];
        *(uint4*)(dst + (d0 + crow) * 2048 + s0 + r8) = p.u;
    }
}

// lam[h] = exp(sum(lq1*lk1)) - exp(sum(lq2*lk2)) + lam_init[h]
__global__ void lam_kernel(const float* __restrict__ lq1, const float* __restrict__ lk1,
                           const float* __restrict__ lq2, const float* __restrict__ lk2,
                           const float* __restrict__ lam_init, float* __restrict__ lam_out) {
    int tid = threadIdx.x; int hh = tid >> 4, i = tid & 15;
    float s1 = 0.f, s2 = 0.f;
#pragma unroll
    for (int j = 0; j < 16; ++j) {
        int d = i + j * 16;
        s1 += lq1[hh * 256 + d] * lk1[hh * 256 + d];
        s2 += lq2[hh * 256 + d] * lk2[hh * 256 + d];
    }
#pragma unroll
    for (int msk = 1; msk < 16; msk <<= 1) { s1 += __shfl_xor(s1, msk); s2 += __shfl_xor(s2, msk); }
    if (i == 0) lam_out[hh] = __expf(s1) - __expf(s2) + lam_init[hh];
}

// ---------------------------------------------------------------- projection GEMM
// C(M=4096, N=4096) = A(4096,256) * BT(4096,256)^T + bias; out layout [b][h][t][d] bf16
__global__ __launch_bounds__(256) void proj_gemm(
    const bf16* __restrict__ xb, const bf16* __restrict__ eb,
    const bf16* __restrict__ WTq, const bf16* __restrict__ WTk, const bf16* __restrict__ WTv,
    const float* __restrict__ bq, const float* __restrict__ bk, const float* __restrict__ bv,
    bf16* __restrict__ Qb, bf16* __restrict__ Kb, bf16* __restrict__ Vb) {
    int z = blockIdx.z;
    const bf16* A = (z == 0) ? xb : eb;
    const bf16* BT = (z == 0) ? WTq : (z == 1) ? WTk : WTv;
    const float* bias = (z == 0) ? bq : (z == 1) ? bk : bv;
    bf16* out = (z == 0) ? Qb : (z == 1) ? Kb : Vb;

    __shared__ alignas(16) bf16 As[128 * 32];
    __shared__ alignas(16) bf16 Bs[128 * 32];
    int m0 = blockIdx.x * 128, n0 = blockIdx.y * 128;
    int tid = threadIdx.x, w = tid >> 6, lane = tid & 63;
    int lrow = lane & 15, lgrp = lane >> 4, lk8 = lgrp * 8;
    int wr = (w >> 1) * 64, wc = (w & 1) * 64;

    f32x4 acc[4][4];
#pragma unroll
    for (int i = 0; i < 4; ++i)
#pragma unroll
        for (int j = 0; j < 4; ++j) acc[i][j] = (f32x4){0.f, 0.f, 0.f, 0.f};

    for (int k0 = 0; k0 < 256; k0 += 32) {
        __syncthreads();
#pragma unroll
        for (int t = 0; t < 2; ++t) {
            int c = tid + t * 256;
            int row = c >> 2, k8 = (c & 3) * 8;
            load_lds16(A + (m0 + row) * 256 + k0 + k8, &As[c * 8]);
            load_lds16(BT + (n0 + row) * 256 + k0 + k8, &Bs[c * 8]);
        }
        __syncthreads();
        bf16x8 af[4], bfr[4];
#pragma unroll
        for (int f = 0; f < 4; ++f) af[f] = *(const bf16x8*)&As[(wr + f * 16 + lrow) * 32 + lk8];
#pragma unroll
        for (int f = 0; f < 4; ++f) bfr[f] = *(const bf16x8*)&Bs[(wc + f * 16 + lrow) * 32 + lk8];
#pragma unroll
        for (int i = 0; i < 4; ++i)
#pragma unroll
            for (int j = 0; j < 4; ++j) acc[i][j] = MFMA16(af[i], bfr[j], acc[i][j]);
    }
#pragma unroll
    for (int i = 0; i < 4; ++i) {
#pragma unroll
        for (int j = 0; j < 4; ++j) {
            int n = n0 + wc + j * 16 + lrow;
            float bvv = bias[n];
            int hh = n >> 8, d = n & 255;
#pragma unroll
            for (int r = 0; r < 4; ++r) {
                int m = m0 + wr + i * 16 + lgrp * 4 + r;
                int bb = m >> 11, tt = m & 2047;
                out[(((size_t)bb * 16 + hh) * 2048 + tt) * 256 + d] = (bf16)(acc[i][j][r] + bvv);
            }
        }
    }
}

// ---------------------------------------------------------------- attention
__device__ __forceinline__ void softmax_pv(f32x4 (&s)[2], float (&mm)[4], float (&ll)[4],
                                           f32x4 (&oo)[16], bf16* Pw, const bf16* VTs,
                                           int lrow, int lgrp, int lk8) {
    float mt[4];
#pragma unroll
    for (int r = 0; r < 4; ++r) {
        s[0][r] *= SCALE_QK; s[1][r] *= SCALE_QK;
        mt[r] = fmaxf(s[0][r], s[1][r]);
    }
#pragma unroll
    for (int msk = 1; msk < 16; msk <<= 1)
#pragma unroll
        for (int r = 0; r < 4; ++r) mt[r] = fmaxf(mt[r], __shfl_xor(mt[r], msk));
    float corr[4], rs[4];
#pragma unroll
    for (int r = 0; r < 4; ++r) {
        float mn = fmaxf(mm[r], mt[r]);
        corr[r] = __expf(mm[r] - mn);
        mm[r] = mn;
        float p0 = __expf(s[0][r] - mn);
        float p1 = __expf(s[1][r] - mn);
        s[0][r] = p0; s[1][r] = p1; rs[r] = p0 + p1;
    }
#pragma unroll
    for (int msk = 1; msk < 16; msk <<= 1)
#pragma unroll
        for (int r = 0; r < 4; ++r) rs[r] += __shfl_xor(rs[r], msk);
#pragma unroll
    for (int r = 0; r < 4; ++r) {
        ll[r] = ll[r] * corr[r] + rs[r];
        Pw[(lgrp * 4 + r) * 40 + lrow] = (bf16)s[0][r];
        Pw[(lgrp * 4 + r) * 40 + 16 + lrow] = (bf16)s[1][r];
    }
#pragma unroll
    for (int df = 0; df < 16; ++df)
#pragma unroll
        for (int r = 0; r < 4; ++r) oo[df][r] *= corr[r];
    bf16x8 pa = *(const bf16x8*)&Pw[lrow * 40 + lk8];
#pragma unroll
    for (int df = 0; df < 16; ++df) {
        bf16x8 vb = *(const bf16x8*)&VTs[(df * 16 + lrow) * 40 + lk8];
        oo[df] = MFMA16(pa, vb, oo[df]);
    }
}

__global__ __launch_bounds__(256, 2) void attn_kernel(
    const bf16* __restrict__ Qb, const bf16* __restrict__ Kb, const bf16* __restrict__ VTb,
    const float* __restrict__ lam_ws, const float* __restrict__ g, bf16* __restrict__ On) {
    __shared__ alignas(16) bf16 Ks[32 * 264];
    __shared__ alignas(16) bf16 VTs[256 * 40];
    __shared__ alignas(16) bf16 Ps[4][16 * 40];
    int bh = blockIdx.y, b = bh >> 4, h = bh & 15;
    int q0 = blockIdx.x * 64;
    int tid = threadIdx.x, w = tid >> 6, lane = tid & 63;
    int lrow = lane & 15, lgrp = lane >> 4, lk8 = lgrp * 8;

    const bf16* Qg = Qb + ((size_t)bh * 2048 + q0 + w * 16) * 256;
    bf16x8 qf[8];
#pragma unroll
    for (int kk = 0; kk < 8; ++kk)
        qf[kk] = *(const bf16x8*)(Qg + lrow * 256 + kk * 32 + lk8);

    f32x4 o1[16], o2[16];
#pragma unroll
    for (int i = 0; i < 16; ++i) { o1[i] = (f32x4){0.f,0.f,0.f,0.f}; o2[i] = (f32x4){0.f,0.f,0.f,0.f}; }
    float m1[4], l1[4], m2[4], l2[4];
#pragma unroll
    for (int r = 0; r < 4; ++r) { m1[r] = -1e30f; l1[r] = 0.f; m2[r] = -1e30f; l2[r] = 0.f; }

    const bf16* Kg = Kb + (size_t)bh * 2048 * 256;
    const bf16* VTg = VTb + (size_t)bh * 256 * 2048;

    for (int kt = 0; kt < 64; ++kt) {
        int s0 = kt * 32;
        __syncthreads();
#pragma unroll
        for (int t = 0; t < 4; ++t) {
            int c = tid + t * 256;
            int row = c >> 5, d8 = (c & 31) * 8;
            *(uint4*)&Ks[row * 264 + d8] = *(const uint4*)(Kg + (s0 + row) * 256 + d8);
        }
#pragma unroll
        for (int t = 0; t < 4; ++t) {
            int c = tid + t * 256;
            int dd = c >> 2, s8 = (c & 3) * 8;
            *(uint4*)&VTs[dd * 40 + s8] = *(const uint4*)(VTg + dd * 2048 + s0 + s8);
        }
        __syncthreads();
        // branch 1 (first 128 dims)
        {
            f32x4 s[2] = {(f32x4){0.f,0.f,0.f,0.f}, (f32x4){0.f,0.f,0.f,0.f}};
#pragma unroll
            for (int kk = 0; kk < 4; ++kk) {
                bf16x8 b0 = *(const bf16x8*)&Ks[lrow * 264 + kk * 32 + lk8];
                bf16x8 b1 = *(const bf16x8*)&Ks[(16 + lrow) * 264 + kk * 32 + lk8];
                s[0] = MFMA16(qf[kk], b0, s[0]);
                s[1] = MFMA16(qf[kk], b1, s[1]);
            }
            softmax_pv(s, m1, l1, o1, &Ps[w][0], VTs, lrow, lgrp, lk8);
        }
        // branch 2 (second 128 dims)
        {
            f32x4 s[2] = {(f32x4){0.f,0.f,0.f,0.f}, (f32x4){0.f,0.f,0.f,0.f}};
#pragma unroll
            for (int kk = 0; kk < 4; ++kk) {
                bf16x8 b0 = *(const bf16x8*)&Ks[lrow * 264 + 128 + kk * 32 + lk8];
                bf16x8 b1 = *(const bf16x8*)&Ks[(16 + lrow) * 264 + 128 + kk * 32 + lk8];
                s[0] = MFMA16(qf[4 + kk], b0, s[0]);
                s[1] = MFMA16(qf[4 + kk], b1, s[1]);
            }
            softmax_pv(s, m2, l2, o2, &Ps[w][0], VTs, lrow, lgrp, lk8);
        }
    }
    // epilogue: combine, RMS-norm, scale, store
    float lam = lam_ws[h];
    float i1[4], i2[4], ssq[4];
#pragma unroll
    for (int r = 0; r < 4; ++r) { i1[r] = 1.f / l1[r]; i2[r] = 1.f / l2[r]; ssq[r] = 0.f; }
#pragma unroll
    for (int df = 0; df < 16; ++df)
#pragma unroll
        for (int r = 0; r < 4; ++r) {
            float v = o1[df][r] * i1[r] - lam * (o2[df][r] * i2[r]);
            o1[df][r] = v;
            ssq[r] += v * v;
        }
#pragma unroll
    for (int msk = 1; msk < 16; msk <<= 1)
#pragma unroll
        for (int r = 0; r < 4; ++r) ssq[r] += __shfl_xor(ssq[r], msk);
    float rinv[4];
#pragma unroll
    for (int r = 0; r < 4; ++r) rinv[r] = 1.f / sqrtf(ssq[r] * (1.f / 256.f) + RMS_EPS);
#pragma unroll
    for (int df = 0; df < 16; ++df) {
        int d = df * 16 + lrow;
        float gv = g[h * 256 + d] * OUT_SCALE;
#pragma unroll
        for (int r = 0; r < 4; ++r) {
            int t = q0 + w * 16 + lgrp * 4 + r;
            On[((size_t)b * 2048 + t) * 4096 + h * 256 + d] = (bf16)(o1[df][r] * rinv[r] * gv);
        }
    }
}

// ---------------------------------------------------------------- output GEMM
// out(4096,256) f32 = On(4096,4096)bf16 * WoT(256,4096)^T + bo
__global__ __launch_bounds__(256) void out_gemm(const bf16* __restrict__ A, const bf16* __restrict__ BT,
                                                const float* __restrict__ bo, float* __restrict__ out) {
    __shared__ alignas(16) bf16 As[64 * 32];
    __shared__ alignas(16) bf16 Bs[64 * 32];
    int m0 = blockIdx.x * 64, n0 = blockIdx.y * 64;
    int tid = threadIdx.x, w = tid >> 6, lane = tid & 63;
    int lrow = lane & 15, lgrp = lane >> 4, lk8 = lgrp * 8;
    int wr = (w >> 1) * 32, wc = (w & 1) * 32;
    f32x4 acc[2][2];
#pragma unroll
    for (int i = 0; i < 2; ++i)
#pragma unroll
        for (int j = 0; j < 2; ++j) acc[i][j] = (f32x4){0.f, 0.f, 0.f, 0.f};
    for (int k0 = 0; k0 < 4096; k0 += 32) {
        __syncthreads();
        int row = tid >> 2, k8 = (tid & 3) * 8;
        load_lds16(A + (size_t)(m0 + row) * 4096 + k0 + k8, &As[tid * 8]);
        load_lds16(BT + (size_t)(n0 + row) * 4096 + k0 + k8, &Bs[tid * 8]);
        __syncthreads();
        bf16x8 af[2], bfr[2];
#pragma unroll
        for (int f = 0; f < 2; ++f) {
            af[f] = *(const bf16x8*)&As[(wr + f * 16 + lrow) * 32 + lk8];
            bfr[f] = *(const bf16x8*)&Bs[(wc + f * 16 + lrow) * 32 + lk8];
        }
#pragma unroll
        for (int i = 0; i < 2; ++i)
#pragma unroll
            for (int j = 0; j < 2; ++j) acc[i][j] = MFMA16(af[i], bfr[j], acc[i][j]);
    }
#pragma unroll
    for (int i = 0; i < 2; ++i)
#pragma unroll
        for (int j = 0; j < 2; ++j) {
            int n = n0 + wc + j * 16 + lrow;
            float bv = bo[n];
#pragma unroll
            for (int r = 0; r < 4; ++r) {
                int m = m0 + wr + i * 16 + lgrp * 4 + r;
                out[(size_t)m * 256 + n] = acc[i][j][r] + bv;
            }
        }
}

// ---------------------------------------------------------------- launch
extern "C" void kernel_launch(void* const* d_in, const int* in_sizes, int n_in,
                              void* d_out, int out_size, void* d_ws, size_t ws_size,
                              hipStream_t stream) {
    const float* x = (const float*)d_in[0];
    const float* enc = (const float*)d_in[1];
    const float* Wq = (const float*)d_in[2];
    const float* bq = (const float*)d_in[3];
    const float* Wk = (const float*)d_in[4];
    const float* bk = (const float*)d_in[5];
    const float* Wv = (const float*)d_in[6];
    const float* bv = (const float*)d_in[7];
    const float* lq1 = (const float*)d_in[8];
    const float* lk1 = (const float*)d_in[9];
    const float* lq2 = (const float*)d_in[10];
    const float* lk2 = (const float*)d_in[11];
    const float* lam_init = (const float*)d_in[12];
    const float* g = (const float*)d_in[13];
    const float* Wo = (const float*)d_in[14];
    const float* bo = (const float*)d_in[15];
    float* out = (float*)d_out;

    char* ws = (char*)d_ws;
    const size_t MB = 1024 * 1024;
    bf16* xb  = (bf16*)(ws + 0 * MB);
    bf16* eb  = (bf16*)(ws + 2 * MB);
    bf16* WTq = (bf16*)(ws + 4 * MB);
    bf16* WTk = (bf16*)(ws + 6 * MB);
    bf16* WTv = (bf16*)(ws + 8 * MB);
    bf16* WoT = (bf16*)(ws + 10 * MB);
    float* lam = (float*)(ws + 12 * MB);
    bf16* Qb  = (bf16*)(ws + 13 * MB);
    bf16* Kb  = (bf16*)(ws + 45 * MB);
    bf16* Vb  = (bf16*)(ws + 77 * MB);
    bf16* VTb = (bf16*)(ws + 109 * MB);
    bf16* On  = Vb;   // Vb is dead after txp_v -> reuse as normalized-O buffer

    hipLaunchKernelGGL(cvt_act, dim3(1024), dim3(256), 0, stream, x, enc, xb, eb);
    hipLaunchKernelGGL(txp_w, dim3(4, 4, 48), dim3(256), 0, stream, Wq, Wk, Wv, WTq, WTk, WTv);
    hipLaunchKernelGGL(txp_wo, dim3(4, 64, 1), dim3(256), 0, stream, Wo, WoT);
    hipLaunchKernelGGL(lam_kernel, dim3(1), dim3(256), 0, stream, lq1, lk1, lq2, lk2, lam_init, lam);
    hipLaunchKernelGGL(proj_gemm, dim3(32, 32, 3), dim3(256), 0, stream,
                       xb, eb, WTq, WTk, WTv, bq, bk, bv, Qb, Kb, Vb);
    hipLaunchKernelGGL(txp_v, dim3(32, 4, 32), dim3(256), 0, stream, Vb, VTb);
    hipLaunchKernelGGL(attn_kernel, dim3(32, 32), dim3(256), 0, stream, Qb, Kb, VTb, lam, g, On);
    hipLaunchKernelGGL(out_gemm, dim3(64, 4), dim3(256), 0, stream, On, WoT, bo, out);
}

// Round 2
// 528.110 us; speedup vs baseline: 1.9396x; 1.9396x over previous
//
#include <hip/hip_runtime.h>
#include <hip/hip_bf16.h>
#include <stdint.h>

typedef __bf16 bf16;
typedef __bf16 bf16x8 __attribute__((ext_vector_type(8)));
typedef float f32x4 __attribute__((ext_vector_type(4)));
typedef unsigned int u32;

#define MFMA16(a, b, c) __builtin_amdgcn_mfma_f32_16x16x32_bf16(a, b, c, 0, 0, 0)

typedef const u32 __attribute__((address_space(1)))* gptr1;
typedef u32 __attribute__((address_space(3)))* lptr3;

__device__ __forceinline__ void load_lds16(const void* g, void* l) {
    __builtin_amdgcn_global_load_lds((gptr1)g, (lptr3)l, 16, 0, 0);
}

#define SCALE_QK 0.08838834764831845f   // 1/sqrt(128)
#define RMS_EPS 1.1920929e-07f
#define OUT_SCALE 0.2f                   // 1 - LAMBDA_INIT
#define DEFER_THR 8.0f

// ---------------------------------------------------------------- converts
__global__ void cvt_act(const float* __restrict__ x, const float* __restrict__ enc,
                        bf16* __restrict__ xb, bf16* __restrict__ eb) {
    int gid = blockIdx.x * 256 + threadIdx.x;   // 0..262143
    const float* src = (gid < 131072) ? x : enc;
    bf16* dst = (gid < 131072) ? xb : eb;
    int i = (gid & 131071) * 8;
    float4 v0 = *(const float4*)(src + i);
    float4 v1 = *(const float4*)(src + i + 4);
    union { bf16 h[8]; uint4 u; } p;
    p.h[0] = (bf16)v0.x; p.h[1] = (bf16)v0.y; p.h[2] = (bf16)v0.z; p.h[3] = (bf16)v0.w;
    p.h[4] = (bf16)v1.x; p.h[5] = (bf16)v1.y; p.h[6] = (bf16)v1.z; p.h[7] = (bf16)v1.w;
    *(uint4*)(dst + i) = p.u;
}

// Wq/Wk/Wv (H,E,DH) f32  ->  WT (H*DH, E) bf16  (per-h 256x256 transpose)
__global__ void txp_w(const float* __restrict__ Wq, const float* __restrict__ Wk,
                      const float* __restrict__ Wv,
                      bf16* __restrict__ WTq, bf16* __restrict__ WTk, bf16* __restrict__ WTv) {
    int z = blockIdx.z; int iw = z >> 4, hh = z & 15;
    const float* src = (iw == 0 ? Wq : iw == 1 ? Wk : Wv) + hh * 65536;
    bf16* dst = (iw == 0 ? WTq : iw == 1 ? WTk : WTv) + hh * 65536;
    __shared__ bf16 T[64][68];
    int r0 = blockIdx.y * 64, c0 = blockIdx.x * 64;
    int tid = threadIdx.x;
#pragma unroll
    for (int t = 0; t < 4; ++t) {
        int idx = tid + t * 256;
        int row = idx >> 4, c4 = (idx & 15) * 4;
        float4 v = *(const float4*)(src + (r0 + row) * 256 + c0 + c4);
        T[row][c4] = (bf16)v.x; T[row][c4 + 1] = (bf16)v.y;
        T[row][c4 + 2] = (bf16)v.z; T[row][c4 + 3] = (bf16)v.w;
    }
    __syncthreads();
#pragma unroll
    for (int t = 0; t < 2; ++t) {
        int idx = tid + t * 256;
        int crow = idx >> 3, r8 = (idx & 7) * 8;
        union { bf16 h[8]; uint4 u; } p;
#pragma unroll
        for (int j = 0; j < 8; ++j) p.h[j] = T[r8 + j][crow];
        *(uint4*)(dst + (c0 + crow) * 256 + r0 + r8) = p.u;
    }
}

// Wo (D=4096, E=256) f32 -> WoT (256, 4096) bf16
__global__ void txp_wo(const float* __restrict__ Wo, bf16* __restrict__ WoT) {
    __shared__ bf16 T[64][68];
    int r0 = blockIdx.y * 64, c0 = blockIdx.x * 64;
    int tid = threadIdx.x;
#pragma unroll
    for (int t = 0; t < 4; ++t) {
        int idx = tid + t * 256;
        int row = idx >> 4, c4 = (idx & 15) * 4;
        float4 v = *(const float4*)(Wo + (size_t)(r0 + row) * 256 + c0 + c4);
        T[row][c4] = (bf16)v.x; T[row][c4 + 1] = (bf16)v.y;
        T[row][c4 + 2] = (bf16)v.z; T[row][c4 + 3] = (bf16)v.w;
    }
    __syncthreads();
#pragma unroll
    for (int t = 0; t < 2; ++t) {
        int idx = tid + t * 256;
        int crow = idx >> 3, r8 = (idx & 7) * 8;
        union { bf16 h[8]; uint4 u; } p;
#pragma unroll
        for (int j = 0; j < 8; ++j) p.h[j] = T[r8 + j][crow];
        *(uint4*)(WoT + (size_t)(c0 + crow) * 4096 + r0 + r8) = p.u;
    }
}

// V [bh][2048][256] bf16 -> VT [bh][256][2048] bf16
__global__ void txp_v(const bf16* __restrict__ V, bf16* __restrict__ VT) {
    int bh = blockIdx.z;
    const bf16* src = V + (size_t)bh * 2048 * 256;
    bf16* dst = VT + (size_t)bh * 256 * 2048;
    __shared__ bf16 T[64][68];
    int s0 = blockIdx.x * 64, d0 = blockIdx.y * 64;
    int tid = threadIdx.x;
#pragma unroll
    for (int t = 0; t < 2; ++t) {
        int idx = tid + t * 256;
        int row = idx >> 3, c8 = (idx & 7) * 8;
        uint4 v = *(const uint4*)(src + (s0 + row) * 256 + d0 + c8);
        *(uint2*)&T[row][c8] = make_uint2(v.x, v.y);
        *(uint2*)&T[row][c8 + 4] = make_uint2(v.z, v.w);
    }
    __syncthreads();
#pragma unroll
    for (int t = 0; t < 2; ++t) {
        int idx = tid + t * 256;
        int crow = idx >> 3, r8 = (idx & 7) * 8;
        union { bf16 h[8]; uint4 u; } p;
#pragma unroll
        for (int j = 0; j < 8; ++j) p.h[j] = T[r8 + j][crow];
        *(uint4*)(dst + (d0 + crow) * 2048 + s0 + r8) = p.u;
    }
}

// lam[h] = exp(sum(lq1*lk1)) - exp(sum(lq2*lk2)) + lam_init[h]
__global__ void lam_kernel(const float* __restrict__ lq1, const float* __restrict__ lk1,
                           const float* __restrict__ lq2, const float* __restrict__ lk2,
                           const float* __restrict__ lam_init, float* __restrict__ lam_out) {
    int tid = threadIdx.x; int hh = tid >> 4, i = tid & 15;
    float s1 = 0.f, s2 = 0.f;
#pragma unroll
    for (int j = 0; j < 16; ++j) {
        int d = i + j * 16;
        s1 += lq1[hh * 256 + d] * lk1[hh * 256 + d];
        s2 += lq2[hh * 256 + d] * lk2[hh * 256 + d];
    }
#pragma unroll
    for (int msk = 1; msk < 16; msk <<= 1) { s1 += __shfl_xor(s1, msk); s2 += __shfl_xor(s2, msk); }
    if (i == 0) lam_out[hh] = __expf(s1) - __expf(s2) + lam_init[hh];
}

// ---------------------------------------------------------------- projection GEMM
// C(M=4096, N=4096) = A(4096,256) * BT(4096,256)^T + bias; out layout [b][h][t][d] bf16
// Q (z==0) is pre-scaled by 1/sqrt(128) so attention skips the scale.
__global__ __launch_bounds__(256) void proj_gemm(
    const bf16* __restrict__ xb, const bf16* __restrict__ eb,
    const bf16* __restrict__ WTq, const bf16* __restrict__ WTk, const bf16* __restrict__ WTv,
    const float* __restrict__ bq, const float* __restrict__ bk, const float* __restrict__ bv,
    bf16* __restrict__ Qb, bf16* __restrict__ Kb, bf16* __restrict__ Vb) {
    int z = blockIdx.z;
    const bf16* A = (z == 0) ? xb : eb;
    const bf16* BT = (z == 0) ? WTq : (z == 1) ? WTk : WTv;
    const float* bias = (z == 0) ? bq : (z == 1) ? bk : bv;
    bf16* out = (z == 0) ? Qb : (z == 1) ? Kb : Vb;
    float qs = (z == 0) ? SCALE_QK : 1.0f;

    __shared__ alignas(16) bf16 As[128 * 32];
    __shared__ alignas(16) bf16 Bs[128 * 32];
    int m0 = blockIdx.x * 128, n0 = blockIdx.y * 128;
    int tid = threadIdx.x, w = tid >> 6, lane = tid & 63;
    int lrow = lane & 15, lgrp = lane >> 4, lk8 = lgrp * 8;
    int wr = (w >> 1) * 64, wc = (w & 1) * 64;

    f32x4 acc[4][4];
#pragma unroll
    for (int i = 0; i < 4; ++i)
#pragma unroll
        for (int j = 0; j < 4; ++j) acc[i][j] = (f32x4){0.f, 0.f, 0.f, 0.f};

    for (int k0 = 0; k0 < 256; k0 += 32) {
        __syncthreads();
#pragma unroll
        for (int t = 0; t < 2; ++t) {
            int c = tid + t * 256;
            int row = c >> 2, k8 = (c & 3) * 8;
            load_lds16(A + (m0 + row) * 256 + k0 + k8, &As[c * 8]);
            load_lds16(BT + (n0 + row) * 256 + k0 + k8, &Bs[c * 8]);
        }
        __syncthreads();
        bf16x8 af[4], bfr[4];
#pragma unroll
        for (int f = 0; f < 4; ++f) af[f] = *(const bf16x8*)&As[(wr + f * 16 + lrow) * 32 + lk8];
#pragma unroll
        for (int f = 0; f < 4; ++f) bfr[f] = *(const bf16x8*)&Bs[(wc + f * 16 + lrow) * 32 + lk8];
#pragma unroll
        for (int i = 0; i < 4; ++i)
#pragma unroll
            for (int j = 0; j < 4; ++j) acc[i][j] = MFMA16(af[i], bfr[j], acc[i][j]);
    }
#pragma unroll
    for (int i = 0; i < 4; ++i) {
#pragma unroll
        for (int j = 0; j < 4; ++j) {
            int n = n0 + wc + j * 16 + lrow;
            float bvv = bias[n];
            int hh = n >> 8, d = n & 255;
#pragma unroll
            for (int r = 0; r < 4; ++r) {
                int m = m0 + wr + i * 16 + lgrp * 4 + r;
                int bb = m >> 11, tt = m & 2047;
                out[(((size_t)bb * 16 + hh) * 2048 + tt) * 256 + d] = (bf16)((acc[i][j][r] + bvv) * qs);
            }
        }
    }
}

// ---------------------------------------------------------------- attention
// 2-phase async pipeline, KBLK=32, merged dual-branch, swizzled K tile.
// LDS: K[2][32][256] (32KB) + VT[2][256][32] (32KB) + P[4][16][72] (9KB) = 73KB -> 2 blocks/CU.
__global__ __launch_bounds__(256, 2) void attn_kernel(
    const bf16* __restrict__ Qb, const bf16* __restrict__ Kb, const bf16* __restrict__ VTb,
    const float* __restrict__ lam_ws, const float* __restrict__ g, bf16* __restrict__ On) {
    __shared__ alignas(16) bf16 Ks[2][32 * 256];
    __shared__ alignas(16) bf16 VTs[2][256 * 32];
    __shared__ alignas(16) bf16 Ps[4][16 * 72];

    // XCD-aware mapping: each XCD gets 4 consecutive bh (K/V L2 reuse).
    int orig = blockIdx.x;            // 0..1023
    int xcd = orig & 7, idx = orig >> 3;
    int bh = xcd * 4 + (idx >> 5);    // 0..31
    int qb = idx & 31;                // 0..31
    int b = bh >> 4, h = bh & 15;
    int q0 = qb * 64;

    int tid = threadIdx.x, w = tid >> 6, lane = tid & 63;
    int lrow = lane & 15, lgrp = lane >> 4, lk8 = lgrp * 8;
    int sw = (lrow & 7) << 2;         // K-read swizzle (bits 2-4 of 16B-slot col)

    const bf16* Qg = Qb + ((size_t)bh * 2048 + q0 + w * 16) * 256;
    bf16x8 qf[8];
#pragma unroll
    for (int kk = 0; kk < 8; ++kk)
        qf[kk] = *(const bf16x8*)(Qg + lrow * 256 + kk * 32 + lk8);

    f32x4 o1[16], o2[16];
#pragma unroll
    for (int i = 0; i < 16; ++i) { o1[i] = (f32x4){0.f,0.f,0.f,0.f}; o2[i] = (f32x4){0.f,0.f,0.f,0.f}; }
    float m1[4], l1[4], m2[4], l2[4];
#pragma unroll
    for (int r = 0; r < 4; ++r) { m1[r] = -1e30f; l1[r] = 0.f; m2[r] = -1e30f; l2[r] = 0.f; }

    const bf16* Kg = Kb + (size_t)bh * 2048 * 256;
    const bf16* VTg = VTb + (size_t)bh * 256 * 2048;
    bf16* Pw = &Ps[w][0];

    // stage tile kt into buffer buf (K swizzled via pre-swizzled global source; VT linear)
    auto STAGE = [&](int buf, int kt) {
        int s0 = kt * 32;
#pragma unroll
        for (int i = 0; i < 4; ++i) {
            int s = i * 256 + tid;                 // 16B-slot index, lane-contiguous per wave
            int row = s >> 5;
            int c16 = (s & 31) ^ ((row & 7) << 2);
            load_lds16(Kg + (size_t)(s0 + row) * 256 + c16 * 8, &Ks[buf][s * 8]);
        }
#pragma unroll
        for (int i = 0; i < 4; ++i) {
            int s = i * 256 + tid;
            int row = s >> 2, c = s & 3;
            load_lds16(VTg + (size_t)row * 2048 + s0 + c * 8, &VTs[buf][s * 8]);
        }
    };

    STAGE(0, 0);
    __syncthreads();

    int cur = 0;
    for (int kt = 0; kt < 64; ++kt) {
        if (kt + 1 < 64) STAGE(cur ^ 1, kt + 1);

        const bf16* Kbuf = &Ks[cur][0];
        const bf16* Vbuf = &VTs[cur][0];

        // ---- QK^T both branches (keys a: rows lrow 0-15, b: rows 16-31)
        f32x4 s1a = (f32x4){0.f,0.f,0.f,0.f}, s1b = s1a, s2a = s1a, s2b = s1a;
#pragma unroll
        for (int kk = 0; kk < 4; ++kk) {
            int c1 = (kk * 4 + lgrp) ^ sw;
            int c2 = (16 + kk * 4 + lgrp) ^ sw;
            bf16x8 k1a = *(const bf16x8*)&Kbuf[lrow * 256 + (c1 << 3)];
            bf16x8 k1b = *(const bf16x8*)&Kbuf[(16 + lrow) * 256 + (c1 << 3)];
            bf16x8 k2a = *(const bf16x8*)&Kbuf[lrow * 256 + (c2 << 3)];
            bf16x8 k2b = *(const bf16x8*)&Kbuf[(16 + lrow) * 256 + (c2 << 3)];
            s1a = MFMA16(qf[kk], k1a, s1a);
            s1b = MFMA16(qf[kk], k1b, s1b);
            s2a = MFMA16(qf[4 + kk], k2a, s2a);
            s2b = MFMA16(qf[4 + kk], k2b, s2b);
        }

        // ---- dual online softmax (interleaved chains)
        float mt1[4], mt2[4];
#pragma unroll
        for (int r = 0; r < 4; ++r) {
            mt1[r] = fmaxf(s1a[r], s1b[r]);
            mt2[r] = fmaxf(s2a[r], s2b[r]);
        }
#pragma unroll
        for (int msk = 1; msk < 16; msk <<= 1)
#pragma unroll
            for (int r = 0; r < 4; ++r) {
                mt1[r] = fmaxf(mt1[r], __shfl_xor(mt1[r], msk));
                mt2[r] = fmaxf(mt2[r], __shfl_xor(mt2[r], msk));
            }
        // defer-max: rescale only when max grew by > DEFER_THR
        bool ok1 = (mt1[0] <= m1[0] + DEFER_THR) && (mt1[1] <= m1[1] + DEFER_THR) &&
                   (mt1[2] <= m1[2] + DEFER_THR) && (mt1[3] <= m1[3] + DEFER_THR);
        if (!__all(ok1)) {
            float c[4];
#pragma unroll
            for (int r = 0; r < 4; ++r) {
                float mn = fmaxf(m1[r], mt1[r]);
                c[r] = __expf(m1[r] - mn);
                m1[r] = mn; l1[r] *= c[r];
            }
#pragma unroll
            for (int df = 0; df < 16; ++df)
#pragma unroll
                for (int r = 0; r < 4; ++r) o1[df][r] *= c[r];
        }
        bool ok2 = (mt2[0] <= m2[0] + DEFER_THR) && (mt2[1] <= m2[1] + DEFER_THR) &&
                   (mt2[2] <= m2[2] + DEFER_THR) && (mt2[3] <= m2[3] + DEFER_THR);
        if (!__all(ok2)) {
            float c[4];
#pragma unroll
            for (int r = 0; r < 4; ++r) {
                float mn = fmaxf(m2[r], mt2[r]);
                c[r] = __expf(m2[r] - mn);
                m2[r] = mn; l2[r] *= c[r];
            }
#pragma unroll
            for (int df = 0; df < 16; ++df)
#pragma unroll
                for (int r = 0; r < 4; ++r) o2[df][r] *= c[r];
        }
        float rs1[4], rs2[4];
#pragma unroll
        for (int r = 0; r < 4; ++r) {
            float p10 = __expf(s1a[r] - m1[r]);
            float p11 = __expf(s1b[r] - m1[r]);
            float p20 = __expf(s2a[r] - m2[r]);
            float p21 = __expf(s2b[r] - m2[r]);
            rs1[r] = p10 + p11; rs2[r] = p20 + p21;
            int prow = (lgrp * 4 + r) * 72;
            Pw[prow + lrow] = (bf16)p10;
            Pw[prow + 16 + lrow] = (bf16)p11;
            Pw[prow + 32 + lrow] = (bf16)p20;
            Pw[prow + 48 + lrow] = (bf16)p21;
        }
#pragma unroll
        for (int msk = 1; msk < 16; msk <<= 1)
#pragma unroll
            for (int r = 0; r < 4; ++r) {
                rs1[r] += __shfl_xor(rs1[r], msk);
                rs2[r] += __shfl_xor(rs2[r], msk);
            }
#pragma unroll
        for (int r = 0; r < 4; ++r) { l1[r] += rs1[r]; l2[r] += rs2[r]; }

        // ---- PV merged: each V fragment feeds both branches
        bf16x8 pa1 = *(const bf16x8*)&Pw[lrow * 72 + lk8];
        bf16x8 pa2 = *(const bf16x8*)&Pw[lrow * 72 + 32 + lk8];
#pragma unroll
        for (int df = 0; df < 16; ++df) {
            bf16x8 vb = *(const bf16x8*)&Vbuf[(df * 16 + lrow) * 32 + lk8];
            o1[df] = MFMA16(pa1, vb, o1[df]);
            o2[df] = MFMA16(pa2, vb, o2[df]);
        }

        __syncthreads();   // drains vmcnt: next tile's staged data is ready
        cur ^= 1;
    }

    // ---- epilogue: combine, RMS-norm, scale, store
    float lam = lam_ws[h];
    float i1[4], i2[4], ssq[4];
#pragma unroll
    for (int r = 0; r < 4; ++r) { i1[r] = 1.f / l1[r]; i2[r] = lam / l2[r]; ssq[r] = 0.f; }
#pragma unroll
    for (int df = 0; df < 16; ++df)
#pragma unroll
        for (int r = 0; r < 4; ++r) {
            float v = o1[df][r] * i1[r] - o2[df][r] * i2[r];
            o1[df][r] = v;
            ssq[r] += v * v;
        }
#pragma unroll
    for (int msk = 1; msk < 16; msk <<= 1)
#pragma unroll
        for (int r = 0; r < 4; ++r) ssq[r] += __shfl_xor(ssq[r], msk);
    float rinv[4];
#pragma unroll
    for (int r = 0; r < 4; ++r) rinv[r] = 1.f / sqrtf(ssq[r] * (1.f / 256.f) + RMS_EPS);
#pragma unroll
    for (int df = 0; df < 16; ++df) {
        int d = df * 16 + lrow;
        float gv = g[h * 256 + d] * OUT_SCALE;
#pragma unroll
        for (int r = 0; r < 4; ++r) {
            int t = q0 + w * 16 + lgrp * 4 + r;
            On[((size_t)b * 2048 + t) * 4096 + h * 256 + d] = (bf16)(o1[df][r] * rinv[r] * gv);
        }
    }
}

// ---------------------------------------------------------------- output GEMM
// out(4096,256) f32 = On(4096,4096)bf16 * WoT(256,4096)^T + bo
__global__ __launch_bounds__(256) void out_gemm(const bf16* __restrict__ A, const bf16* __restrict__ BT,
                                                const float* __restrict__ bo, float* __restrict__ out) {
    __shared__ alignas(16) bf16 As[64 * 32];
    __shared__ alignas(16) bf16 Bs[64 * 32];
    int m0 = blockIdx.x * 64, n0 = blockIdx.y * 64;
    int tid = threadIdx.x, w = tid >> 6, lane = tid & 63;
    int lrow = lane & 15, lgrp = lane >> 4, lk8 = lgrp * 8;
    int wr = (w >> 1) * 32, wc = (w & 1) * 32;
    f32x4 acc[2][2];
#pragma unroll
    for (int i = 0; i < 2; ++i)
#pragma unroll
        for (int j = 0; j < 2; ++j) acc[i][j] = (f32x4){0.f, 0.f, 0.f, 0.f};
    for (int k0 = 0; k0 < 4096; k0 += 32) {
        __syncthreads();
        int row = tid >> 2, k8 = (tid & 3) * 8;
        load_lds16(A + (size_t)(m0 + row) * 4096 + k0 + k8, &As[tid * 8]);
        load_lds16(BT + (size_t)(n0 + row) * 4096 + k0 + k8, &Bs[tid * 8]);
        __syncthreads();
        bf16x8 af[2], bfr[2];
#pragma unroll
        for (int f = 0; f < 2; ++f) {
            af[f] = *(const bf16x8*)&As[(wr + f * 16 + lrow) * 32 + lk8];
            bfr[f] = *(const bf16x8*)&Bs[(wc + f * 16 + lrow) * 32 + lk8];
        }
#pragma unroll
        for (int i = 0; i < 2; ++i)
#pragma unroll
            for (int j = 0; j < 2; ++j) acc[i][j] = MFMA16(af[i], bfr[j], acc[i][j]);
    }
#pragma unroll
    for (int i = 0; i < 2; ++i)
#pragma unroll
        for (int j = 0; j < 2; ++j) {
            int n = n0 + wc + j * 16 + lrow;
            float bv = bo[n];
#pragma unroll
            for (int r = 0; r < 4; ++r) {
                int m = m0 + wr + i * 16 + lgrp * 4 + r;
                out[(size_t)m * 256 + n] = acc[i][j][r] + bv;
            }
        }
}

// ---------------------------------------------------------------- launch
extern "C" void kernel_launch(void* const* d_in, const int* in_sizes, int n_in,
                              void* d_out, int out_size, void* d_ws, size_t ws_size,
                              hipStream_t stream) {
    const float* x = (const float*)d_in[0];
    const float* enc = (const float*)d_in[1];
    const float* Wq = (const float*)d_in[2];
    const float* bq = (const float*)d_in[3];
    const float* Wk = (const float*)d_in[4];
    const float* bk = (const float*)d_in[5];
    const float* Wv = (const float*)d_in[6];
    const float* bv = (const float*)d_in[7];
    const float* lq1 = (const float*)d_in[8];
    const float* lk1 = (const float*)d_in[9];
    const float* lq2 = (const float*)d_in[10];
    const float* lk2 = (const float*)d_in[11];
    const float* lam_init = (const float*)d_in[12];
    const float* g = (const float*)d_in[13];
    const float* Wo = (const float*)d_in[14];
    const float* bo = (const float*)d_in[15];
    float* out = (float*)d_out;

    char* ws = (char*)d_ws;
    const size_t MB = 1024 * 1024;
    bf16* xb  = (bf16*)(ws + 0 * MB);
    bf16* eb  = (bf16*)(ws + 2 * MB);
    bf16* WTq = (bf16*)(ws + 4 * MB);
    bf16* WTk = (bf16*)(ws + 6 * MB);
    bf16* WTv = (bf16*)(ws + 8 * MB);
    bf16* WoT = (bf16*)(ws + 10 * MB);
    float* lam = (float*)(ws + 12 * MB);
    bf16* Qb  = (bf16*)(ws + 13 * MB);
    bf16* Kb  = (bf16*)(ws + 45 * MB);
    bf16* Vb  = (bf16*)(ws + 77 * MB);
    bf16* VTb = (bf16*)(ws + 109 * MB);
    bf16* On  = Vb;   // Vb is dead after txp_v -> reuse as normalized-O buffer

    hipLaunchKernelGGL(cvt_act, dim3(1024), dim3(256), 0, stream, x, enc, xb, eb);
    hipLaunchKernelGGL(txp_w, dim3(4, 4, 48), dim3(256), 0, stream, Wq, Wk, Wv, WTq, WTk, WTv);
    hipLaunchKernelGGL(txp_wo, dim3(4, 64, 1), dim3(256), 0, stream, Wo, WoT);
    hipLaunchKernelGGL(lam_kernel, dim3(1), dim3(256), 0, stream, lq1, lk1, lq2, lk2, lam_init, lam);
    hipLaunchKernelGGL(proj_gemm, dim3(32, 32, 3), dim3(256), 0, stream,
                       xb, eb, WTq, WTk, WTv, bq, bk, bv, Qb, Kb, Vb);
    hipLaunchKernelGGL(txp_v, dim3(32, 4, 32), dim3(256), 0, stream, Vb, VTb);
    hipLaunchKernelGGL(attn_kernel, dim3(1024), dim3(256), 0, stream, Qb, Kb, VTb, lam, g, On);
    hipLaunchKernelGGL(out_gemm, dim3(64, 4), dim3(256), 0, stream, On, WoT, bo, out);
}

// Round 4
// 385.760 us; speedup vs baseline: 2.6554x; 1.3690x over previous
//
#include <hip/hip_runtime.h>
#include <hip/hip_bf16.h>
#include <stdint.h>
#include <math.h>

typedef __bf16 bf16;
typedef __bf16 bf16x8 __attribute__((ext_vector_type(8)));
typedef float f32x4 __attribute__((ext_vector_type(4)));
typedef unsigned int u32;

#define MFMA16(a, b, c) __builtin_amdgcn_mfma_f32_16x16x32_bf16(a, b, c, 0, 0, 0)

typedef const u32 __attribute__((address_space(1)))* gptr1;
typedef u32 __attribute__((address_space(3)))* lptr3;

__device__ __forceinline__ void load_lds16(const void* g, void* l) {
    __builtin_amdgcn_global_load_lds((gptr1)g, (lptr3)l, 16, 0, 0);
}

#define SCALE_QK 0.08838834764831845f    // 1/sqrt(128)
#define LOG2E 1.4426950408889634f
#define QK_PRESCALE (SCALE_QK * LOG2E)   // folded into Q at projection
#define RMS_EPS 1.1920929e-07f
#define OUT_SCALE 0.2f                   // 1 - LAMBDA_INIT
#define DEFER_THR 8.0f                   // log2 units: p <= 2^8

// ---------------------------------------------------------------- converts
__global__ void cvt_act(const float* __restrict__ x, const float* __restrict__ enc,
                        bf16* __restrict__ xb, bf16* __restrict__ eb) {
    int gid = blockIdx.x * 256 + threadIdx.x;   // 0..262143
    const float* src = (gid < 131072) ? x : enc;
    bf16* dst = (gid < 131072) ? xb : eb;
    int i = (gid & 131071) * 8;
    float4 v0 = *(const float4*)(src + i);
    float4 v1 = *(const float4*)(src + i + 4);
    union { bf16 h[8]; uint4 u; } p;
    p.h[0] = (bf16)v0.x; p.h[1] = (bf16)v0.y; p.h[2] = (bf16)v0.z; p.h[3] = (bf16)v0.w;
    p.h[4] = (bf16)v1.x; p.h[5] = (bf16)v1.y; p.h[6] = (bf16)v1.z; p.h[7] = (bf16)v1.w;
    *(uint4*)(dst + i) = p.u;
}

// Wq/Wk/Wv (H,E,DH) f32  ->  WT (H*DH, E) bf16  (per-h 256x256 transpose)
__global__ void txp_w(const float* __restrict__ Wq, const float* __restrict__ Wk,
                      const float* __restrict__ Wv,
                      bf16* __restrict__ WTq, bf16* __restrict__ WTk, bf16* __restrict__ WTv) {
    int z = blockIdx.z; int iw = z >> 4, hh = z & 15;
    const float* src = (iw == 0 ? Wq : iw == 1 ? Wk : Wv) + hh * 65536;
    bf16* dst = (iw == 0 ? WTq : iw == 1 ? WTk : WTv) + hh * 65536;
    __shared__ bf16 T[64][68];
    int r0 = blockIdx.y * 64, c0 = blockIdx.x * 64;
    int tid = threadIdx.x;
#pragma unroll
    for (int t = 0; t < 4; ++t) {
        int idx = tid + t * 256;
        int row = idx >> 4, c4 = (idx & 15) * 4;
        float4 v = *(const float4*)(src + (r0 + row) * 256 + c0 + c4);
        T[row][c4] = (bf16)v.x; T[row][c4 + 1] = (bf16)v.y;
        T[row][c4 + 2] = (bf16)v.z; T[row][c4 + 3] = (bf16)v.w;
    }
    __syncthreads();
#pragma unroll
    for (int t = 0; t < 2; ++t) {
        int idx = tid + t * 256;
        int crow = idx >> 3, r8 = (idx & 7) * 8;
        union { bf16 h[8]; uint4 u; } p;
#pragma unroll
        for (int j = 0; j < 8; ++j) p.h[j] = T[r8 + j][crow];
        *(uint4*)(dst + (c0 + crow) * 256 + r0 + r8) = p.u;
    }
}

// Wo (D=4096, E=256) f32 -> WoT (256, 4096) bf16
__global__ void txp_wo(const float* __restrict__ Wo, bf16* __restrict__ WoT) {
    __shared__ bf16 T[64][68];
    int r0 = blockIdx.y * 64, c0 = blockIdx.x * 64;
    int tid = threadIdx.x;
#pragma unroll
    for (int t = 0; t < 4; ++t) {
        int idx = tid + t * 256;
        int row = idx >> 4, c4 = (idx & 15) * 4;
        float4 v = *(const float4*)(Wo + (size_t)(r0 + row) * 256 + c0 + c4);
        T[row][c4] = (bf16)v.x; T[row][c4 + 1] = (bf16)v.y;
        T[row][c4 + 2] = (bf16)v.z; T[row][c4 + 3] = (bf16)v.w;
    }
    __syncthreads();
#pragma unroll
    for (int t = 0; t < 2; ++t) {
        int idx = tid + t * 256;
        int crow = idx >> 3, r8 = (idx & 7) * 8;
        union { bf16 h[8]; uint4 u; } p;
#pragma unroll
        for (int j = 0; j < 8; ++j) p.h[j] = T[r8 + j][crow];
        *(uint4*)(WoT + (size_t)(c0 + crow) * 4096 + r0 + r8) = p.u;
    }
}

// V [bh][2048][256] bf16 -> VT [bh][256][2048] bf16
__global__ void txp_v(const bf16* __restrict__ V, bf16* __restrict__ VT) {
    int bh = blockIdx.z;
    const bf16* src = V + (size_t)bh * 2048 * 256;
    bf16* dst = VT + (size_t)bh * 256 * 2048;
    __shared__ bf16 T[64][68];
    int s0 = blockIdx.x * 64, d0 = blockIdx.y * 64;
    int tid = threadIdx.x;
#pragma unroll
    for (int t = 0; t < 2; ++t) {
        int idx = tid + t * 256;
        int row = idx >> 3, c8 = (idx & 7) * 8;
        uint4 v = *(const uint4*)(src + (s0 + row) * 256 + d0 + c8);
        *(uint2*)&T[row][c8] = make_uint2(v.x, v.y);
        *(uint2*)&T[row][c8 + 4] = make_uint2(v.z, v.w);
    }
    __syncthreads();
#pragma unroll
    for (int t = 0; t < 2; ++t) {
        int idx = tid + t * 256;
        int crow = idx >> 3, r8 = (idx & 7) * 8;
        union { bf16 h[8]; uint4 u; } p;
#pragma unroll
        for (int j = 0; j < 8; ++j) p.h[j] = T[r8 + j][crow];
        *(uint4*)(dst + (d0 + crow) * 2048 + s0 + r8) = p.u;
    }
}

// lam[h] = exp(sum(lq1*lk1)) - exp(sum(lq2*lk2)) + lam_init[h]
__global__ void lam_kernel(const float* __restrict__ lq1, const float* __restrict__ lk1,
                           const float* __restrict__ lq2, const float* __restrict__ lk2,
                           const float* __restrict__ lam_init, float* __restrict__ lam_out) {
    int tid = threadIdx.x; int hh = tid >> 4, i = tid & 15;
    float s1 = 0.f, s2 = 0.f;
#pragma unroll
    for (int j = 0; j < 16; ++j) {
        int d = i + j * 16;
        s1 += lq1[hh * 256 + d] * lk1[hh * 256 + d];
        s2 += lq2[hh * 256 + d] * lk2[hh * 256 + d];
    }
#pragma unroll
    for (int msk = 1; msk < 16; msk <<= 1) { s1 += __shfl_xor(s1, msk); s2 += __shfl_xor(s2, msk); }
    if (i == 0) lam_out[hh] = __expf(s1) - __expf(s2) + lam_init[hh];
}

// ---------------------------------------------------------------- projection GEMM
// C(M=4096, N=4096) = A(4096,256) * BT(4096,256)^T + bias; out layout [b][h][t][d] bf16
// Q (z==0) is pre-scaled by (1/sqrt(128))*log2(e) so attention uses exp2 directly.
__global__ __launch_bounds__(256) void proj_gemm(
    const bf16* __restrict__ xb, const bf16* __restrict__ eb,
    const bf16* __restrict__ WTq, const bf16* __restrict__ WTk, const bf16* __restrict__ WTv,
    const float* __restrict__ bq, const float* __restrict__ bk, const float* __restrict__ bv,
    bf16* __restrict__ Qb, bf16* __restrict__ Kb, bf16* __restrict__ Vb) {
    int z = blockIdx.z;
    const bf16* A = (z == 0) ? xb : eb;
    const bf16* BT = (z == 0) ? WTq : (z == 1) ? WTk : WTv;
    const float* bias = (z == 0) ? bq : (z == 1) ? bk : bv;
    bf16* out = (z == 0) ? Qb : (z == 1) ? Kb : Vb;
    float qs = (z == 0) ? QK_PRESCALE : 1.0f;

    __shared__ alignas(16) bf16 As[128 * 32];
    __shared__ alignas(16) bf16 Bs[128 * 32];
    int m0 = blockIdx.x * 128, n0 = blockIdx.y * 128;
    int tid = threadIdx.x, w = tid >> 6, lane = tid & 63;
    int lrow = lane & 15, lgrp = lane >> 4, lk8 = lgrp * 8;
    int wr = (w >> 1) * 64, wc = (w & 1) * 64;

    f32x4 acc[4][4];
#pragma unroll
    for (int i = 0; i < 4; ++i)
#pragma unroll
        for (int j = 0; j < 4; ++j) acc[i][j] = (f32x4){0.f, 0.f, 0.f, 0.f};

    for (int k0 = 0; k0 < 256; k0 += 32) {
        __syncthreads();
#pragma unroll
        for (int t = 0; t < 2; ++t) {
            int c = tid + t * 256;
            int row = c >> 2, k8 = (c & 3) * 8;
            load_lds16(A + (m0 + row) * 256 + k0 + k8, &As[c * 8]);
            load_lds16(BT + (n0 + row) * 256 + k0 + k8, &Bs[c * 8]);
        }
        __syncthreads();
        bf16x8 af[4], bfr[4];
#pragma unroll
        for (int f = 0; f < 4; ++f) af[f] = *(const bf16x8*)&As[(wr + f * 16 + lrow) * 32 + lk8];
#pragma unroll
        for (int f = 0; f < 4; ++f) bfr[f] = *(const bf16x8*)&Bs[(wc + f * 16 + lrow) * 32 + lk8];
#pragma unroll
        for (int i = 0; i < 4; ++i)
#pragma unroll
            for (int j = 0; j < 4; ++j) acc[i][j] = MFMA16(af[i], bfr[j], acc[i][j]);
    }
#pragma unroll
    for (int i = 0; i < 4; ++i) {
#pragma unroll
        for (int j = 0; j < 4; ++j) {
            int n = n0 + wc + j * 16 + lrow;
            float bvv = bias[n];
            int hh = n >> 8, d = n & 255;
#pragma unroll
            for (int r = 0; r < 4; ++r) {
                int m = m0 + wr + i * 16 + lgrp * 4 + r;
                int bb = m >> 11, tt = m & 2047;
                out[(((size_t)bb * 16 + hh) * 2048 + tt) * 256 + d] = (bf16)((acc[i][j][r] + bvv) * qs);
            }
        }
    }
}

// ---------------------------------------------------------------- attention
// 2-phase async pipeline, KBLK=32, merged dual-branch.
// Correct bank swizzles: K slot ^= row&7 ; VT slot ^= (row>>1)&3 (both-sides involution).
// No per-tile cross-lane reductions: per-lane l partials + __all defer-max check.
__global__ __launch_bounds__(256, 2) void attn_kernel(
    const bf16* __restrict__ Qb, const bf16* __restrict__ Kb, const bf16* __restrict__ VTb,
    const float* __restrict__ lam_ws, const float* __restrict__ g, bf16* __restrict__ On) {
    __shared__ alignas(16) bf16 Ks[2][32 * 256];
    __shared__ alignas(16) bf16 VTs[2][256 * 32];
    __shared__ alignas(16) bf16 Ps[4][16 * 72];

    // XCD-aware mapping: each XCD gets 4 consecutive bh (K/V L2 reuse).
    int orig = blockIdx.x;            // 0..1023
    int xcd = orig & 7, idx = orig >> 3;
    int bh = xcd * 4 + (idx >> 5);    // 0..31
    int qb = idx & 31;                // 0..31
    int b = bh >> 4, h = bh & 15;
    int q0 = qb * 64;

    int tid = threadIdx.x, w = tid >> 6, lane = tid & 63;
    int lrow = lane & 15, lgrp = lane >> 4, lk8 = lgrp * 8;
    int ksw = lrow & 7;               // K read swizzle (low 3 bits of 16B-slot col)
    int vsw = (lrow >> 1) & 3;        // VT read swizzle

    const bf16* Qg = Qb + ((size_t)bh * 2048 + q0 + w * 16) * 256;
    bf16x8 qf[8];
#pragma unroll
    for (int kk = 0; kk < 8; ++kk)
        qf[kk] = *(const bf16x8*)(Qg + lrow * 256 + kk * 32 + lk8);

    f32x4 o1[16], o2[16];
#pragma unroll
    for (int i = 0; i < 16; ++i) { o1[i] = (f32x4){0.f,0.f,0.f,0.f}; o2[i] = (f32x4){0.f,0.f,0.f,0.f}; }
    float m1[4], l1[4], m2[4], l2[4];
#pragma unroll
    for (int r = 0; r < 4; ++r) { m1[r] = -1e30f; l1[r] = 0.f; m2[r] = -1e30f; l2[r] = 0.f; }

    const bf16* Kg = Kb + (size_t)bh * 2048 * 256;
    const bf16* VTg = VTb + (size_t)bh * 256 * 2048;
    bf16* Pw = &Ps[w][0];

    // stage tile kt into buffer buf; LDS dest linear, global source inverse-swizzled
    auto STAGE = [&](int buf, int kt) {
        int s0 = kt * 32;
#pragma unroll
        for (int i = 0; i < 4; ++i) {
            int s = i * 256 + tid;                  // 16B-slot index
            int row = s >> 5;
            int cg = (s & 31) ^ (row & 7);
            load_lds16(Kg + (size_t)(s0 + row) * 256 + cg * 8, &Ks[buf][s * 8]);
        }
#pragma unroll
        for (int i = 0; i < 4; ++i) {
            int s = i * 256 + tid;
            int row = s >> 2;
            int cg = (s & 3) ^ ((row >> 1) & 3);
            load_lds16(VTg + (size_t)row * 2048 + s0 + cg * 8, &VTs[buf][s * 8]);
        }
    };

    STAGE(0, 0);
    __syncthreads();

    int cur = 0;
    for (int kt = 0; kt < 64; ++kt) {
        if (kt + 1 < 64) STAGE(cur ^ 1, kt + 1);

        const bf16* Kbuf = &Ks[cur][0];
        const bf16* Vbuf = &VTs[cur][0];

        // ---- QK^T both branches (keys a: rows 0-15, b: rows 16-31)
        f32x4 s1a = (f32x4){0.f,0.f,0.f,0.f}, s1b = s1a, s2a = s1a, s2b = s1a;
        __builtin_amdgcn_s_setprio(1);
#pragma unroll
        for (int kk = 0; kk < 4; ++kk) {
            int c1 = (kk * 4 + lgrp) ^ ksw;
            int c2 = (16 + kk * 4 + lgrp) ^ ksw;
            bf16x8 k1a = *(const bf16x8*)&Kbuf[lrow * 256 + (c1 << 3)];
            bf16x8 k1b = *(const bf16x8*)&Kbuf[(16 + lrow) * 256 + (c1 << 3)];
            bf16x8 k2a = *(const bf16x8*)&Kbuf[lrow * 256 + (c2 << 3)];
            bf16x8 k2b = *(const bf16x8*)&Kbuf[(16 + lrow) * 256 + (c2 << 3)];
            s1a = MFMA16(qf[kk], k1a, s1a);
            s1b = MFMA16(qf[kk], k1b, s1b);
            s2a = MFMA16(qf[4 + kk], k2a, s2a);
            s2b = MFMA16(qf[4 + kk], k2b, s2b);
        }
        __builtin_amdgcn_s_setprio(0);

        // ---- deferred-max online softmax, no cross-lane ops on common path
        float lmx1 = fmaxf(fmaxf(s1a[0], s1b[0]), fmaxf(s1a[1], s1b[1]));
        lmx1 = fmaxf(lmx1, fmaxf(fmaxf(s1a[2], s1b[2]), fmaxf(s1a[3], s1b[3])));
        float lmx2 = fmaxf(fmaxf(s2a[0], s2b[0]), fmaxf(s2a[1], s2b[1]));
        lmx2 = fmaxf(lmx2, fmaxf(fmaxf(s2a[2], s2b[2]), fmaxf(s2a[3], s2b[3])));
        float mmin1 = fminf(fminf(m1[0], m1[1]), fminf(m1[2], m1[3]));
        float mmin2 = fminf(fminf(m2[0], m2[1]), fminf(m2[2], m2[3]));

        if (!__all((lmx1 <= mmin1 + DEFER_THR) ? 1 : 0)) {
            float mt[4];
#pragma unroll
            for (int r = 0; r < 4; ++r) mt[r] = fmaxf(s1a[r], s1b[r]);
#pragma unroll
            for (int msk = 1; msk < 16; msk <<= 1)
#pragma unroll
                for (int r = 0; r < 4; ++r) mt[r] = fmaxf(mt[r], __shfl_xor(mt[r], msk));
            float c[4];
#pragma unroll
            for (int r = 0; r < 4; ++r) {
                float mn = fmaxf(m1[r], mt[r]);
                c[r] = exp2f(m1[r] - mn);
                m1[r] = mn; l1[r] *= c[r];
            }
#pragma unroll
            for (int df = 0; df < 16; ++df)
#pragma unroll
                for (int r = 0; r < 4; ++r) o1[df][r] *= c[r];
        }
        if (!__all((lmx2 <= mmin2 + DEFER_THR) ? 1 : 0)) {
            float mt[4];
#pragma unroll
            for (int r = 0; r < 4; ++r) mt[r] = fmaxf(s2a[r], s2b[r]);
#pragma unroll
            for (int msk = 1; msk < 16; msk <<= 1)
#pragma unroll
                for (int r = 0; r < 4; ++r) mt[r] = fmaxf(mt[r], __shfl_xor(mt[r], msk));
            float c[4];
#pragma unroll
            for (int r = 0; r < 4; ++r) {
                float mn = fmaxf(m2[r], mt[r]);
                c[r] = exp2f(m2[r] - mn);
                m2[r] = mn; l2[r] *= c[r];
            }
#pragma unroll
            for (int df = 0; df < 16; ++df)
#pragma unroll
                for (int r = 0; r < 4; ++r) o2[df][r] *= c[r];
        }
#pragma unroll
        for (int r = 0; r < 4; ++r) {
            float p10 = exp2f(s1a[r] - m1[r]);
            float p11 = exp2f(s1b[r] - m1[r]);
            float p20 = exp2f(s2a[r] - m2[r]);
            float p21 = exp2f(s2b[r] - m2[r]);
            l1[r] += p10 + p11;           // per-lane partial; reduced in epilogue
            l2[r] += p20 + p21;
            int prow = (lgrp * 4 + r) * 72;
            Pw[prow + lrow] = (bf16)p10;
            Pw[prow + 16 + lrow] = (bf16)p11;
            Pw[prow + 32 + lrow] = (bf16)p20;
            Pw[prow + 48 + lrow] = (bf16)p21;
        }

        // ---- PV merged: each V fragment feeds both branches
        bf16x8 pa1 = *(const bf16x8*)&Pw[lrow * 72 + lk8];
        bf16x8 pa2 = *(const bf16x8*)&Pw[lrow * 72 + 32 + lk8];
        __builtin_amdgcn_s_setprio(1);
#pragma unroll
        for (int df = 0; df < 16; ++df) {
            int vc = lgrp ^ vsw;          // row parity folds out: (df*16+lrow)>>1 & 3 == (lrow>>1)&3
            bf16x8 vb = *(const bf16x8*)&Vbuf[(df * 16 + lrow) * 32 + (vc << 3)];
            o1[df] = MFMA16(pa1, vb, o1[df]);
            o2[df] = MFMA16(pa2, vb, o2[df]);
        }
        __builtin_amdgcn_s_setprio(0);

        __syncthreads();   // drains vmcnt: next tile's staged data is ready
        cur ^= 1;
    }

    // ---- epilogue: reduce l partials, combine, RMS-norm, scale, store
#pragma unroll
    for (int msk = 1; msk < 16; msk <<= 1)
#pragma unroll
        for (int r = 0; r < 4; ++r) {
            l1[r] += __shfl_xor(l1[r], msk);
            l2[r] += __shfl_xor(l2[r], msk);
        }
    float lam = lam_ws[h];
    float i1[4], i2[4], ssq[4];
#pragma unroll
    for (int r = 0; r < 4; ++r) { i1[r] = 1.f / l1[r]; i2[r] = lam / l2[r]; ssq[r] = 0.f; }
#pragma unroll
    for (int df = 0; df < 16; ++df)
#pragma unroll
        for (int r = 0; r < 4; ++r) {
            float v = o1[df][r] * i1[r] - o2[df][r] * i2[r];
            o1[df][r] = v;
            ssq[r] += v * v;
        }
#pragma unroll
    for (int msk = 1; msk < 16; msk <<= 1)
#pragma unroll
        for (int r = 0; r < 4; ++r) ssq[r] += __shfl_xor(ssq[r], msk);
    float rinv[4];
#pragma unroll
    for (int r = 0; r < 4; ++r) rinv[r] = 1.f / sqrtf(ssq[r] * (1.f / 256.f) + RMS_EPS);
#pragma unroll
    for (int df = 0; df < 16; ++df) {
        int d = df * 16 + lrow;
        float gv = g[h * 256 + d] * OUT_SCALE;
#pragma unroll
        for (int r = 0; r < 4; ++r) {
            int t = q0 + w * 16 + lgrp * 4 + r;
            On[((size_t)b * 2048 + t) * 4096 + h * 256 + d] = (bf16)(o1[df][r] * rinv[r] * gv);
        }
    }
}

// ---------------------------------------------------------------- output GEMM
// out(4096,256) f32 = On(4096,4096)bf16 * WoT(256,4096)^T + bo
__global__ __launch_bounds__(256) void out_gemm(const bf16* __restrict__ A, const bf16* __restrict__ BT,
                                                const float* __restrict__ bo, float* __restrict__ out) {
    __shared__ alignas(16) bf16 As[64 * 32];
    __shared__ alignas(16) bf16 Bs[64 * 32];
    int m0 = blockIdx.x * 64, n0 = blockIdx.y * 64;
    int tid = threadIdx.x, w = tid >> 6, lane = tid & 63;
    int lrow = lane & 15, lgrp = lane >> 4, lk8 = lgrp * 8;
    int wr = (w >> 1) * 32, wc = (w & 1) * 32;
    f32x4 acc[2][2];
#pragma unroll
    for (int i = 0; i < 2; ++i)
#pragma unroll
        for (int j = 0; j < 2; ++j) acc[i][j] = (f32x4){0.f, 0.f, 0.f, 0.f};
    for (int k0 = 0; k0 < 4096; k0 += 32) {
        __syncthreads();
        int row = tid >> 2, k8 = (tid & 3) * 8;
        load_lds16(A + (size_t)(m0 + row) * 4096 + k0 + k8, &As[tid * 8]);
        load_lds16(BT + (size_t)(n0 + row) * 4096 + k0 + k8, &Bs[tid * 8]);
        __syncthreads();
        bf16x8 af[2], bfr[2];
#pragma unroll
        for (int f = 0; f < 2; ++f) {
            af[f] = *(const bf16x8*)&As[(wr + f * 16 + lrow) * 32 + lk8];
            bfr[f] = *(const bf16x8*)&Bs[(wc + f * 16 + lrow) * 32 + lk8];
        }
#pragma unroll
        for (int i = 0; i < 2; ++i)
#pragma unroll
            for (int j = 0; j < 2; ++j) acc[i][j] = MFMA16(af[i], bfr[j], acc[i][j]);
    }
#pragma unroll
    for (int i = 0; i < 2; ++i)
#pragma unroll
        for (int j = 0; j < 2; ++j) {
            int n = n0 + wc + j * 16 + lrow;
            float bv = bo[n];
#pragma unroll
            for (int r = 0; r < 4; ++r) {
                int m = m0 + wr + i * 16 + lgrp * 4 + r;
                out[(size_t)m * 256 + n] = acc[i][j][r] + bv;
            }
        }
}

// ---------------------------------------------------------------- launch
extern "C" void kernel_launch(void* const* d_in, const int* in_sizes, int n_in,
                              void* d_out, int out_size, void* d_ws, size_t ws_size,
                              hipStream_t stream) {
    const float* x = (const float*)d_in[0];
    const float* enc = (const float*)d_in[1];
    const float* Wq = (const float*)d_in[2];
    const float* bq = (const float*)d_in[3];
    const float* Wk = (const float*)d_in[4];
    const float* bk = (const float*)d_in[5];
    const float* Wv = (const float*)d_in[6];
    const float* bv = (const float*)d_in[7];
    const float* lq1 = (const float*)d_in[8];
    const float* lk1 = (const float*)d_in[9];
    const float* lq2 = (const float*)d_in[10];
    const float* lk2 = (const float*)d_in[11];
    const float* lam_init = (const float*)d_in[12];
    const float* g = (const float*)d_in[13];
    const float* Wo = (const float*)d_in[14];
    const float* bo = (const float*)d_in[15];
    float* out = (float*)d_out;

    char* ws = (char*)d_ws;
    const size_t MB = 1024 * 1024;
    bf16* xb  = (bf16*)(ws + 0 * MB);
    bf16* eb  = (bf16*)(ws + 2 * MB);
    bf16* WTq = (bf16*)(ws + 4 * MB);
    bf16* WTk = (bf16*)(ws + 6 * MB);
    bf16* WTv = (bf16*)(ws + 8 * MB);
    bf16* WoT = (bf16*)(ws + 10 * MB);
    float* lam = (float*)(ws + 12 * MB);
    bf16* Qb  = (bf16*)(ws + 13 * MB);
    bf16* Kb  = (bf16*)(ws + 45 * MB);
    bf16* Vb  = (bf16*)(ws + 77 * MB);
    bf16* VTb = (bf16*)(ws + 109 * MB);
    bf16* On  = Vb;   // Vb is dead after txp_v -> reuse as normalized-O buffer

    hipLaunchKernelGGL(cvt_act, dim3(1024), dim3(256), 0, stream, x, enc, xb, eb);
    hipLaunchKernelGGL(txp_w, dim3(4, 4, 48), dim3(256), 0, stream, Wq, Wk, Wv, WTq, WTk, WTv);
    hipLaunchKernelGGL(txp_wo, dim3(4, 64, 1), dim3(256), 0, stream, Wo, WoT);
    hipLaunchKernelGGL(lam_kernel, dim3(1), dim3(256), 0, stream, lq1, lk1, lq2, lk2, lam_init, lam);
    hipLaunchKernelGGL(proj_gemm, dim3(32, 32, 3), dim3(256), 0, stream,
                       xb, eb, WTq, WTk, WTv, bq, bk, bv, Qb, Kb, Vb);
    hipLaunchKernelGGL(txp_v, dim3(32, 4, 32), dim3(256), 0, stream, Vb, VTb);
    hipLaunchKernelGGL(attn_kernel, dim3(1024), dim3(256), 0, stream, Qb, Kb, VTb, lam, g, On);
    hipLaunchKernelGGL(out_gemm, dim3(64, 4), dim3(256), 0, stream, On, WoT, bo, out);
}

// Round 6
// 375.910 us; speedup vs baseline: 2.7250x; 1.0262x over previous
//
#include <hip/hip_runtime.h>
#include <hip/hip_bf16.h>
#include <stdint.h>
#include <math.h>

typedef __bf16 bf16;
typedef __bf16 bf16x8 __attribute__((ext_vector_type(8)));
typedef float f32x4 __attribute__((ext_vector_type(4)));
typedef float f32x16 __attribute__((ext_vector_type(16)));
typedef unsigned int u32;

#define MFMA16(a, b, c) __builtin_amdgcn_mfma_f32_16x16x32_bf16(a, b, c, 0, 0, 0)
#define MFMA32(a, b, c) __builtin_amdgcn_mfma_f32_32x32x16_bf16(a, b, c, 0, 0, 0)

typedef const u32 __attribute__((address_space(1)))* gptr1;
typedef u32 __attribute__((address_space(3)))* lptr3;

__device__ __forceinline__ void load_lds16(const void* g, void* l) {
    __builtin_amdgcn_global_load_lds((gptr1)g, (lptr3)l, 16, 0, 0);
}

// pack two f32 -> one u32 of 2 bf16 (element 0 in low 16 bits)
__device__ __forceinline__ u32 pk2(float lo, float hi_) {
    union { bf16 h[2]; u32 u; } t;
    t.h[0] = (bf16)lo; t.h[1] = (bf16)hi_;
    return t.u;
}
__device__ __forceinline__ u32 xswap(u32 x) {   // partner-lane (lane^32) value
    return (u32)__shfl_xor((int)x, 32);
}

#define SCALE_QK 0.08838834764831845f    // 1/sqrt(128)
#define LOG2E 1.4426950408889634f
#define QK_PRESCALE (SCALE_QK * LOG2E)   // folded into Q at projection
#define RMS_EPS 1.1920929e-07f
#define OUT_SCALE 0.2f                   // 1 - LAMBDA_INIT
#define DEFER_THR 8.0f                   // log2 units: p <= 2^8

// ---------------------------------------------------------------- converts
__global__ void cvt_act(const float* __restrict__ x, const float* __restrict__ enc,
                        bf16* __restrict__ xb, bf16* __restrict__ eb) {
    int gid = blockIdx.x * 256 + threadIdx.x;
    const float* src = (gid < 131072) ? x : enc;
    bf16* dst = (gid < 131072) ? xb : eb;
    int i = (gid & 131071) * 8;
    float4 v0 = *(const float4*)(src + i);
    float4 v1 = *(const float4*)(src + i + 4);
    union { bf16 h[8]; uint4 u; } p;
    p.h[0] = (bf16)v0.x; p.h[1] = (bf16)v0.y; p.h[2] = (bf16)v0.z; p.h[3] = (bf16)v0.w;
    p.h[4] = (bf16)v1.x; p.h[5] = (bf16)v1.y; p.h[6] = (bf16)v1.z; p.h[7] = (bf16)v1.w;
    *(uint4*)(dst + i) = p.u;
}

__global__ void txp_w(const float* __restrict__ Wq, const float* __restrict__ Wk,
                      const float* __restrict__ Wv,
                      bf16* __restrict__ WTq, bf16* __restrict__ WTk, bf16* __restrict__ WTv) {
    int z = blockIdx.z; int iw = z >> 4, hh = z & 15;
    const float* src = (iw == 0 ? Wq : iw == 1 ? Wk : Wv) + hh * 65536;
    bf16* dst = (iw == 0 ? WTq : iw == 1 ? WTk : WTv) + hh * 65536;
    __shared__ bf16 T[64][68];
    int r0 = blockIdx.y * 64, c0 = blockIdx.x * 64;
    int tid = threadIdx.x;
#pragma unroll
    for (int t = 0; t < 4; ++t) {
        int idx = tid + t * 256;
        int row = idx >> 4, c4 = (idx & 15) * 4;
        float4 v = *(const float4*)(src + (r0 + row) * 256 + c0 + c4);
        T[row][c4] = (bf16)v.x; T[row][c4 + 1] = (bf16)v.y;
        T[row][c4 + 2] = (bf16)v.z; T[row][c4 + 3] = (bf16)v.w;
    }
    __syncthreads();
#pragma unroll
    for (int t = 0; t < 2; ++t) {
        int idx = tid + t * 256;
        int crow = idx >> 3, r8 = (idx & 7) * 8;
        union { bf16 h[8]; uint4 u; } p;
#pragma unroll
        for (int j = 0; j < 8; ++j) p.h[j] = T[r8 + j][crow];
        *(uint4*)(dst + (c0 + crow) * 256 + r0 + r8) = p.u;
    }
}

__global__ void txp_wo(const float* __restrict__ Wo, bf16* __restrict__ WoT) {
    __shared__ bf16 T[64][68];
    int r0 = blockIdx.y * 64, c0 = blockIdx.x * 64;
    int tid = threadIdx.x;
#pragma unroll
    for (int t = 0; t < 4; ++t) {
        int idx = tid + t * 256;
        int row = idx >> 4, c4 = (idx & 15) * 4;
        float4 v = *(const float4*)(Wo + (size_t)(r0 + row) * 256 + c0 + c4);
        T[row][c4] = (bf16)v.x; T[row][c4 + 1] = (bf16)v.y;
        T[row][c4 + 2] = (bf16)v.z; T[row][c4 + 3] = (bf16)v.w;
    }
    __syncthreads();
#pragma unroll
    for (int t = 0; t < 2; ++t) {
        int idx = tid + t * 256;
        int crow = idx >> 3, r8 = (idx & 7) * 8;
        union { bf16 h[8]; uint4 u; } p;
#pragma unroll
        for (int j = 0; j < 8; ++j) p.h[j] = T[r8 + j][crow];
        *(uint4*)(WoT + (size_t)(c0 + crow) * 4096 + r0 + r8) = p.u;
    }
}

__global__ void txp_v(const bf16* __restrict__ V, bf16* __restrict__ VT) {
    int bh = blockIdx.z;
    const bf16* src = V + (size_t)bh * 2048 * 256;
    bf16* dst = VT + (size_t)bh * 256 * 2048;
    __shared__ bf16 T[64][68];
    int s0 = blockIdx.x * 64, d0 = blockIdx.y * 64;
    int tid = threadIdx.x;
#pragma unroll
    for (int t = 0; t < 2; ++t) {
        int idx = tid + t * 256;
        int row = idx >> 3, c8 = (idx & 7) * 8;
        uint4 v = *(const uint4*)(src + (s0 + row) * 256 + d0 + c8);
        *(uint2*)&T[row][c8] = make_uint2(v.x, v.y);
        *(uint2*)&T[row][c8 + 4] = make_uint2(v.z, v.w);
    }
    __syncthreads();
#pragma unroll
    for (int t = 0; t < 2; ++t) {
        int idx = tid + t * 256;
        int crow = idx >> 3, r8 = (idx & 7) * 8;
        union { bf16 h[8]; uint4 u; } p;
#pragma unroll
        for (int j = 0; j < 8; ++j) p.h[j] = T[r8 + j][crow];
        *(uint4*)(dst + (d0 + crow) * 2048 + s0 + r8) = p.u;
    }
}

__global__ void lam_kernel(const float* __restrict__ lq1, const float* __restrict__ lk1,
                           const float* __restrict__ lq2, const float* __restrict__ lk2,
                           const float* __restrict__ lam_init, float* __restrict__ lam_out) {
    int tid = threadIdx.x; int hh = tid >> 4, i = tid & 15;
    float s1 = 0.f, s2 = 0.f;
#pragma unroll
    for (int j = 0; j < 16; ++j) {
        int d = i + j * 16;
        s1 += lq1[hh * 256 + d] * lk1[hh * 256 + d];
        s2 += lq2[hh * 256 + d] * lk2[hh * 256 + d];
    }
#pragma unroll
    for (int msk = 1; msk < 16; msk <<= 1) { s1 += __shfl_xor(s1, msk); s2 += __shfl_xor(s2, msk); }
    if (i == 0) lam_out[hh] = __expf(s1) - __expf(s2) + lam_init[hh];
}

// ---------------------------------------------------------------- projection GEMM
__global__ __launch_bounds__(256) void proj_gemm(
    const bf16* __restrict__ xb, const bf16* __restrict__ eb,
    const bf16* __restrict__ WTq, const bf16* __restrict__ WTk, const bf16* __restrict__ WTv,
    const float* __restrict__ bq, const float* __restrict__ bk, const float* __restrict__ bv,
    bf16* __restrict__ Qb, bf16* __restrict__ Kb, bf16* __restrict__ Vb) {
    int z = blockIdx.z;
    const bf16* A = (z == 0) ? xb : eb;
    const bf16* BT = (z == 0) ? WTq : (z == 1) ? WTk : WTv;
    const float* bias = (z == 0) ? bq : (z == 1) ? bk : bv;
    bf16* out = (z == 0) ? Qb : (z == 1) ? Kb : Vb;
    float qs = (z == 0) ? QK_PRESCALE : 1.0f;

    __shared__ alignas(16) bf16 As[128 * 32];
    __shared__ alignas(16) bf16 Bs[128 * 32];
    int m0 = blockIdx.x * 128, n0 = blockIdx.y * 128;
    int tid = threadIdx.x, w = tid >> 6, lane = tid & 63;
    int lrow = lane & 15, lgrp = lane >> 4, lk8 = lgrp * 8;
    int wr = (w >> 1) * 64, wc = (w & 1) * 64;

    f32x4 acc[4][4];
#pragma unroll
    for (int i = 0; i < 4; ++i)
#pragma unroll
        for (int j = 0; j < 4; ++j) acc[i][j] = (f32x4){0.f, 0.f, 0.f, 0.f};

    for (int k0 = 0; k0 < 256; k0 += 32) {
        __syncthreads();
#pragma unroll
        for (int t = 0; t < 2; ++t) {
            int c = tid + t * 256;
            int row = c >> 2, k8 = (c & 3) * 8;
            load_lds16(A + (m0 + row) * 256 + k0 + k8, &As[c * 8]);
            load_lds16(BT + (n0 + row) * 256 + k0 + k8, &Bs[c * 8]);
        }
        __syncthreads();
        bf16x8 af[4], bfr[4];
#pragma unroll
        for (int f = 0; f < 4; ++f) af[f] = *(const bf16x8*)&As[(wr + f * 16 + lrow) * 32 + lk8];
#pragma unroll
        for (int f = 0; f < 4; ++f) bfr[f] = *(const bf16x8*)&Bs[(wc + f * 16 + lrow) * 32 + lk8];
#pragma unroll
        for (int i = 0; i < 4; ++i)
#pragma unroll
            for (int j = 0; j < 4; ++j) acc[i][j] = MFMA16(af[i], bfr[j], acc[i][j]);
    }
#pragma unroll
    for (int i = 0; i < 4; ++i) {
#pragma unroll
        for (int j = 0; j < 4; ++j) {
            int n = n0 + wc + j * 16 + lrow;
            float bvv = bias[n];
            int hh = n >> 8, d = n & 255;
#pragma unroll
            for (int r = 0; r < 4; ++r) {
                int m = m0 + wr + i * 16 + lgrp * 4 + r;
                int bb = m >> 11, tt = m & 2047;
                out[(((size_t)bb * 16 + hh) * 2048 + tt) * 256 + d] = (bf16)((acc[i][j][r] + bvv) * qs);
            }
        }
    }
}

// ---------------------------------------------------------------- attention
// Branch-split waves, 32x32x16 MFMA, swapped operands (lane-local softmax).
// P exchange via portable __shfl_xor(,32) + selects (no permlane/cvt_pk asm).
__global__ __launch_bounds__(256, 2) void attn_kernel(
    const bf16* __restrict__ Qb, const bf16* __restrict__ Kb, const bf16* __restrict__ VTb,
    const float* __restrict__ lam_ws, const float* __restrict__ g, bf16* __restrict__ On) {
    __shared__ alignas(16) char SMEM[75264];
    bf16* KsB = (bf16*)SMEM;                  // [2][32*256]  (main loop)
    bf16* VsB = (bf16*)(SMEM + 32768);        // [2][256*32]  (main loop)
    float* o2buf  = (float*)SMEM;             // [64][256]    (epilogue, overlays K/V)
    float* smem_c = (float*)(SMEM + 65536);   // [4][32] rescale corr
    float* smem_i = (float*)(SMEM + 66048);   // [128] 1/l1 | lam/l2
    float* smem_r = (float*)(SMEM + 66560);   // [64] rinv
    float* psum   = (float*)(SMEM + 66816);   // [64][33]

    int orig = blockIdx.x;
    int xcd = orig & 7, idx = orig >> 3;
    int bh = xcd * 4 + (idx >> 5);
    int qb = idx & 31;
    int b = bh >> 4, h = bh & 15;
    int q0 = qb * 64;

    int tid = threadIdx.x, w = tid >> 6, lane = tid & 63;
    int lq = lane & 31, hi = lane >> 5;
    int br = w >> 1, qw = (w & 1) * 32;
    int ksw = lq & 7;
    int vsw = (lq >> 1) & 3;
    bool hib = (hi != 0);

    const bf16* Qg = Qb + ((size_t)bh * 2048 + q0 + qw + lq) * 256 + br * 128;
    bf16x8 qf[8];
#pragma unroll
    for (int dk = 0; dk < 8; ++dk)
        qf[dk] = *(const bf16x8*)(Qg + dk * 16 + hi * 8);

    f32x16 o[8];
#pragma unroll
    for (int dt = 0; dt < 8; ++dt)
#pragma unroll
        for (int i = 0; i < 16; ++i) o[dt][i] = 0.f;
    float m = -1e30f, lsum = 0.f;

    const bf16* Kg = Kb + (size_t)bh * 2048 * 256;
    const bf16* VTg = VTb + (size_t)bh * 256 * 2048;

    auto STAGE = [&](int buf, int kt) {
        int s0 = kt * 32;
#pragma unroll
        for (int i = 0; i < 4; ++i) {
            int s = i * 256 + tid;
            int row = s >> 5;
            int cg = (s & 31) ^ (row & 7);
            load_lds16(Kg + (size_t)(s0 + row) * 256 + cg * 8, KsB + buf * 8192 + s * 8);
        }
#pragma unroll
        for (int i = 0; i < 4; ++i) {
            int s = i * 256 + tid;
            int row = s >> 2;
            int cg = (s & 3) ^ ((row >> 1) & 3);
            load_lds16(VTg + (size_t)row * 2048 + s0 + cg * 8, VsB + buf * 8192 + s * 8);
        }
    };

    STAGE(0, 0);
    __syncthreads();

    int cur = 0;
    for (int kt = 0; kt < 64; ++kt) {
        if (kt + 1 < 64) STAGE(cur ^ 1, kt + 1);
        const bf16* Kbuf = KsB + cur * 8192;
        const bf16* Vbuf = VsB + cur * 8192;

        // ---- QK^T: S[key][q] (A = K rows, B = Q rows); 2-way ILP
        f32x16 sa, sb;
#pragma unroll
        for (int i = 0; i < 16; ++i) { sa[i] = 0.f; sb[i] = 0.f; }
        __builtin_amdgcn_s_setprio(1);
#pragma unroll
        for (int dk = 0; dk < 4; ++dk) {
            bf16x8 k0 = *(const bf16x8*)&Kbuf[lq * 256 + (((br * 16 + 4 * dk + hi) ^ ksw) << 3)];
            bf16x8 k1 = *(const bf16x8*)&Kbuf[lq * 256 + (((br * 16 + 4 * dk + 2 + hi) ^ ksw) << 3)];
            sa = MFMA32(k0, qf[2 * dk], sa);
            sb = MFMA32(k1, qf[2 * dk + 1], sb);
        }
        __builtin_amdgcn_s_setprio(0);
        f32x16 sc;
#pragma unroll
        for (int i = 0; i < 16; ++i) sc[i] = sa[i] + sb[i];

        // ---- lane-local online softmax (q = lq; lane holds 16 of 32 keys)
        float m0a = fmaxf(sc[0], sc[1]),  m0b = fmaxf(sc[2], sc[3]);
        float m0c = fmaxf(sc[4], sc[5]),  m0d = fmaxf(sc[6], sc[7]);
        float m0e = fmaxf(sc[8], sc[9]),  m0f = fmaxf(sc[10], sc[11]);
        float m0g = fmaxf(sc[12], sc[13]), m0h = fmaxf(sc[14], sc[15]);
        float mt = fmaxf(fmaxf(fmaxf(m0a, m0b), fmaxf(m0c, m0d)),
                         fmaxf(fmaxf(m0e, m0f), fmaxf(m0g, m0h)));
        mt = fmaxf(mt, __shfl_xor(mt, 32));   // partner half combine

        if (!__all((mt <= m + DEFER_THR) ? 1 : 0)) {
            float mn = fmaxf(m, mt);
            float corr = exp2f(m - mn);
            smem_c[w * 32 + lq] = corr;
            asm volatile("s_waitcnt lgkmcnt(0)" ::: "memory");
            m = mn; lsum *= corr;
#pragma unroll
            for (int r = 0; r < 16; ++r) {
                float cg = smem_c[w * 32 + (r & 3) + 8 * (r >> 2) + 4 * hi];
#pragma unroll
                for (int dt = 0; dt < 8; ++dt) o[dt][r] *= cg;
            }
        }

        float p[16];
        float ls0 = 0.f, ls1 = 0.f;
#pragma unroll
        for (int i = 0; i < 8; ++i) { p[i] = exp2f(sc[i] - m); ls0 += p[i]; }
#pragma unroll
        for (int i = 8; i < 16; ++i) { p[i] = exp2f(sc[i] - m); ls1 += p[i]; }
        lsum += ls0 + ls1;

        // ---- pack P into PV A-fragments (portable cross-half exchange)
        // own pairs: X=(regs0-3), Y=(4-7), Z=(8-11), W=(12-15)
        u32 X0 = pk2(p[0], p[1]),   X1 = pk2(p[2], p[3]);
        u32 Y0 = pk2(p[4], p[5]),   Y1 = pk2(p[6], p[7]);
        u32 Z0 = pk2(p[8], p[9]),   Z1 = pk2(p[10], p[11]);
        u32 W0 = pk2(p[12], p[13]), W1 = pk2(p[14], p[15]);
        u32 pX0 = xswap(X0), pX1 = xswap(X1);
        u32 pY0 = xswap(Y0), pY1 = xswap(Y1);
        u32 pZ0 = xswap(Z0), pZ1 = xswap(Z1);
        u32 pW0 = xswap(W0), pW1 = xswap(W1);
        union { u32 u[4]; bf16x8 v; } PA0, PA1;
        PA0.u[0] = hib ? pY0 : X0;  PA0.u[1] = hib ? pY1 : X1;
        PA0.u[2] = hib ? Y0 : pX0;  PA0.u[3] = hib ? Y1 : pX1;
        PA1.u[0] = hib ? pW0 : Z0;  PA1.u[1] = hib ? pW1 : Z1;
        PA1.u[2] = hib ? W0 : pZ0;  PA1.u[3] = hib ? W1 : pZ1;

        // ---- PV: O[q][d] += P . V  (B = VT rows; 8 independent dt chains)
        __builtin_amdgcn_s_setprio(1);
#pragma unroll
        for (int dt = 0; dt < 8; ++dt) {
            const bf16* vrow = &Vbuf[(dt * 32 + lq) * 32];
            bf16x8 v0 = *(const bf16x8*)&vrow[(hi ^ vsw) << 3];
            o[dt] = MFMA32(PA0.v, v0, o[dt]);
            bf16x8 v1 = *(const bf16x8*)&vrow[((2 + hi) ^ vsw) << 3];
            o[dt] = MFMA32(PA1.v, v1, o[dt]);
        }
        __builtin_amdgcn_s_setprio(0);

        __syncthreads();
        cur ^= 1;
    }

    // ---- epilogue: combine partner l, cross-wave branch combine, RMS, store
    lsum += __shfl_xor(lsum, 32);
    float lam = lam_ws[h];
    float inv = (br == 0) ? 1.f / lsum : lam / lsum;
    smem_i[br * 64 + qw + lq] = inv;
    __syncthreads();

    if (br == 1) {
#pragma unroll
        for (int r = 0; r < 16; ++r) {
            int qp = (r & 3) + 8 * (r >> 2) + 4 * hi + qw;
            float i2 = smem_i[64 + qp];
#pragma unroll
            for (int dt = 0; dt < 8; ++dt)
                o2buf[qp * 256 + dt * 32 + lq] = o[dt][r] * i2;
        }
    }
    __syncthreads();

    if (br == 0) {
#pragma unroll
        for (int r = 0; r < 16; ++r) {
            int qp = (r & 3) + 8 * (r >> 2) + 4 * hi + qw;
            float i1 = smem_i[qp];
            float ss = 0.f;
#pragma unroll
            for (int dt = 0; dt < 8; ++dt) {
                float v = o[dt][r] * i1 - o2buf[qp * 256 + dt * 32 + lq];
                o[dt][r] = v;
                ss += v * v;
            }
            psum[qp * 33 + lq] = ss;
        }
    }
    __syncthreads();

    if (tid < 64) {
        float s = 0.f;
#pragma unroll
        for (int i = 0; i < 32; ++i) s += psum[tid * 33 + i];
        smem_r[tid] = 1.f / sqrtf(s * (1.f / 256.f) + RMS_EPS);
    }
    __syncthreads();

    if (br == 0) {
        float gv[8];
#pragma unroll
        for (int dt = 0; dt < 8; ++dt) gv[dt] = g[h * 256 + dt * 32 + lq] * OUT_SCALE;
#pragma unroll
        for (int r = 0; r < 16; ++r) {
            int qp = (r & 3) + 8 * (r >> 2) + 4 * hi + qw;
            float rv = smem_r[qp];
            size_t base = ((size_t)b * 2048 + q0 + qp) * 4096 + h * 256;
#pragma unroll
            for (int dt = 0; dt < 8; ++dt)
                On[base + dt * 32 + lq] = (bf16)(o[dt][r] * rv * gv[dt]);
        }
    }
}

// ---------------------------------------------------------------- output GEMM
__global__ __launch_bounds__(256) void out_gemm(const bf16* __restrict__ A, const bf16* __restrict__ BT,
                                                const float* __restrict__ bo, float* __restrict__ out) {
    __shared__ alignas(16) bf16 As[64 * 32];
    __shared__ alignas(16) bf16 Bs[64 * 32];
    int m0 = blockIdx.x * 64, n0 = blockIdx.y * 64;
    int tid = threadIdx.x, w = tid >> 6, lane = tid & 63;
    int lrow = lane & 15, lgrp = lane >> 4, lk8 = lgrp * 8;
    int wr = (w >> 1) * 32, wc = (w & 1) * 32;
    f32x4 acc[2][2];
#pragma unroll
    for (int i = 0; i < 2; ++i)
#pragma unroll
        for (int j = 0; j < 2; ++j) acc[i][j] = (f32x4){0.f, 0.f, 0.f, 0.f};
    for (int k0 = 0; k0 < 4096; k0 += 32) {
        __syncthreads();
        int row = tid >> 2, k8 = (tid & 3) * 8;
        load_lds16(A + (size_t)(m0 + row) * 4096 + k0 + k8, &As[tid * 8]);
        load_lds16(BT + (size_t)(n0 + row) * 4096 + k0 + k8, &Bs[tid * 8]);
        __syncthreads();
        bf16x8 af[2], bfr[2];
#pragma unroll
        for (int f = 0; f < 2; ++f) {
            af[f] = *(const bf16x8*)&As[(wr + f * 16 + lrow) * 32 + lk8];
            bfr[f] = *(const bf16x8*)&Bs[(wc + f * 16 + lrow) * 32 + lk8];
        }
#pragma unroll
        for (int i = 0; i < 2; ++i)
#pragma unroll
            for (int j = 0; j < 2; ++j) acc[i][j] = MFMA16(af[i], bfr[j], acc[i][j]);
    }
#pragma unroll
    for (int i = 0; i < 2; ++i)
#pragma unroll
        for (int j = 0; j < 2; ++j) {
            int n = n0 + wc + j * 16 + lrow;
            float bv = bo[n];
#pragma unroll
            for (int r = 0; r < 4; ++r) {
                int m = m0 + wr + i * 16 + lgrp * 4 + r;
                out[(size_t)m * 256 + n] = acc[i][j][r] + bv;
            }
        }
}

// ---------------------------------------------------------------- launch
extern "C" void kernel_launch(void* const* d_in, const int* in_sizes, int n_in,
                              void* d_out, int out_size, void* d_ws, size_t ws_size,
                              hipStream_t stream) {
    const float* x = (const float*)d_in[0];
    const float* enc = (const float*)d_in[1];
    const float* Wq = (const float*)d_in[2];
    const float* bq = (const float*)d_in[3];
    const float* Wk = (const float*)d_in[4];
    const float* bk = (const float*)d_in[5];
    const float* Wv = (const float*)d_in[6];
    const float* bv = (const float*)d_in[7];
    const float* lq1 = (const float*)d_in[8];
    const float* lk1 = (const float*)d_in[9];
    const float* lq2 = (const float*)d_in[10];
    const float* lk2 = (const float*)d_in[11];
    const float* lam_init = (const float*)d_in[12];
    const float* g = (const float*)d_in[13];
    const float* Wo = (const float*)d_in[14];
    const float* bo = (const float*)d_in[15];
    float* out = (float*)d_out;

    char* ws = (char*)d_ws;
    const size_t MB = 1024 * 1024;
    bf16* xb  = (bf16*)(ws + 0 * MB);
    bf16* eb  = (bf16*)(ws + 2 * MB);
    bf16* WTq = (bf16*)(ws + 4 * MB);
    bf16* WTk = (bf16*)(ws + 6 * MB);
    bf16* WTv = (bf16*)(ws + 8 * MB);
    bf16* WoT = (bf16*)(ws + 10 * MB);
    float* lam = (float*)(ws + 12 * MB);
    bf16* Qb  = (bf16*)(ws + 13 * MB);
    bf16* Kb  = (bf16*)(ws + 45 * MB);
    bf16* Vb  = (bf16*)(ws + 77 * MB);
    bf16* VTb = (bf16*)(ws + 109 * MB);
    bf16* On  = Vb;   // Vb dead after txp_v -> reuse

    hipLaunchKernelGGL(cvt_act, dim3(1024), dim3(256), 0, stream, x, enc, xb, eb);
    hipLaunchKernelGGL(txp_w, dim3(4, 4, 48), dim3(256), 0, stream, Wq, Wk, Wv, WTq, WTk, WTv);
    hipLaunchKernelGGL(txp_wo, dim3(4, 64, 1), dim3(256), 0, stream, Wo, WoT);
    hipLaunchKernelGGL(lam_kernel, dim3(1), dim3(256), 0, stream, lq1, lk1, lq2, lk2, lam_init, lam);
    hipLaunchKernelGGL(proj_gemm, dim3(32, 32, 3), dim3(256), 0, stream,
                       xb, eb, WTq, WTk, WTv, bq, bk, bv, Qb, Kb, Vb);
    hipLaunchKernelGGL(txp_v, dim3(32, 4, 32), dim3(256), 0, stream, Vb, VTb);
    hipLaunchKernelGGL(attn_kernel, dim3(1024), dim3(256), 0, stream, Qb, Kb, VTb, lam, g, On);
    hipLaunchKernelGGL(out_gemm, dim3(64, 4), dim3(256), 0, stream, On, WoT, bo, out);
}

// Round 7
// 362.012 us; speedup vs baseline: 2.8296x; 1.0384x over previous
//
#include <hip/hip_runtime.h>
#include <hip/hip_bf16.h>
#include <stdint.h>
#include <math.h>

typedef __bf16 bf16;
typedef __bf16 bf16x8 __attribute__((ext_vector_type(8)));
typedef float f32x4 __attribute__((ext_vector_type(4)));
typedef float f32x16 __attribute__((ext_vector_type(16)));
typedef unsigned int u32;

#define MFMA16(a, b, c) __builtin_amdgcn_mfma_f32_16x16x32_bf16(a, b, c, 0, 0, 0)
#define MFMA32(a, b, c) __builtin_amdgcn_mfma_f32_32x32x16_bf16(a, b, c, 0, 0, 0)

typedef const u32 __attribute__((address_space(1)))* gptr1;
typedef u32 __attribute__((address_space(3)))* lptr3;

__device__ __forceinline__ void load_lds16(const void* g, void* l) {
    __builtin_amdgcn_global_load_lds((gptr1)g, (lptr3)l, 16, 0, 0);
}

// pack two f32 -> one u32 of 2 bf16 (element 0 in low 16 bits)
__device__ __forceinline__ u32 pk2(float lo, float hi_) {
    union { bf16 h[2]; u32 u; } t;
    t.h[0] = (bf16)lo; t.h[1] = (bf16)hi_;
    return t.u;
}
__device__ __forceinline__ u32 xswap(u32 x) {   // partner-lane (lane^32) value
    return (u32)__shfl_xor((int)x, 32);
}

#define SCALE_QK 0.08838834764831845f    // 1/sqrt(128)
#define LOG2E 1.4426950408889634f
#define QK_PRESCALE (SCALE_QK * LOG2E)   // folded into Q at projection
#define RMS_EPS 1.1920929e-07f
#define OUT_SCALE 0.2f                   // 1 - LAMBDA_INIT
#define M0_BIAS (-16.0f)                 // fixed softmax offset (log2 units), folded into QK acc init

// ---------------------------------------------------------------- converts
__global__ void cvt_act(const float* __restrict__ x, const float* __restrict__ enc,
                        bf16* __restrict__ xb, bf16* __restrict__ eb) {
    int gid = blockIdx.x * 256 + threadIdx.x;
    const float* src = (gid < 131072) ? x : enc;
    bf16* dst = (gid < 131072) ? xb : eb;
    int i = (gid & 131071) * 8;
    float4 v0 = *(const float4*)(src + i);
    float4 v1 = *(const float4*)(src + i + 4);
    union { bf16 h[8]; uint4 u; } p;
    p.h[0] = (bf16)v0.x; p.h[1] = (bf16)v0.y; p.h[2] = (bf16)v0.z; p.h[3] = (bf16)v0.w;
    p.h[4] = (bf16)v1.x; p.h[5] = (bf16)v1.y; p.h[6] = (bf16)v1.z; p.h[7] = (bf16)v1.w;
    *(uint4*)(dst + i) = p.u;
}

__global__ void txp_w(const float* __restrict__ Wq, const float* __restrict__ Wk,
                      const float* __restrict__ Wv,
                      bf16* __restrict__ WTq, bf16* __restrict__ WTk, bf16* __restrict__ WTv) {
    int z = blockIdx.z; int iw = z >> 4, hh = z & 15;
    const float* src = (iw == 0 ? Wq : iw == 1 ? Wk : Wv) + hh * 65536;
    bf16* dst = (iw == 0 ? WTq : iw == 1 ? WTk : WTv) + hh * 65536;
    __shared__ bf16 T[64][68];
    int r0 = blockIdx.y * 64, c0 = blockIdx.x * 64;
    int tid = threadIdx.x;
#pragma unroll
    for (int t = 0; t < 4; ++t) {
        int idx = tid + t * 256;
        int row = idx >> 4, c4 = (idx & 15) * 4;
        float4 v = *(const float4*)(src + (r0 + row) * 256 + c0 + c4);
        T[row][c4] = (bf16)v.x; T[row][c4 + 1] = (bf16)v.y;
        T[row][c4 + 2] = (bf16)v.z; T[row][c4 + 3] = (bf16)v.w;
    }
    __syncthreads();
#pragma unroll
    for (int t = 0; t < 2; ++t) {
        int idx = tid + t * 256;
        int crow = idx >> 3, r8 = (idx & 7) * 8;
        union { bf16 h[8]; uint4 u; } p;
#pragma unroll
        for (int j = 0; j < 8; ++j) p.h[j] = T[r8 + j][crow];
        *(uint4*)(dst + (c0 + crow) * 256 + r0 + r8) = p.u;
    }
}

__global__ void txp_wo(const float* __restrict__ Wo, bf16* __restrict__ WoT) {
    __shared__ bf16 T[64][68];
    int r0 = blockIdx.y * 64, c0 = blockIdx.x * 64;
    int tid = threadIdx.x;
#pragma unroll
    for (int t = 0; t < 4; ++t) {
        int idx = tid + t * 256;
        int row = idx >> 4, c4 = (idx & 15) * 4;
        float4 v = *(const float4*)(Wo + (size_t)(r0 + row) * 256 + c0 + c4);
        T[row][c4] = (bf16)v.x; T[row][c4 + 1] = (bf16)v.y;
        T[row][c4 + 2] = (bf16)v.z; T[row][c4 + 3] = (bf16)v.w;
    }
    __syncthreads();
#pragma unroll
    for (int t = 0; t < 2; ++t) {
        int idx = tid + t * 256;
        int crow = idx >> 3, r8 = (idx & 7) * 8;
        union { bf16 h[8]; uint4 u; } p;
#pragma unroll
        for (int j = 0; j < 8; ++j) p.h[j] = T[r8 + j][crow];
        *(uint4*)(WoT + (size_t)(c0 + crow) * 4096 + r0 + r8) = p.u;
    }
}

__global__ void txp_v(const bf16* __restrict__ V, bf16* __restrict__ VT) {
    int bh = blockIdx.z;
    const bf16* src = V + (size_t)bh * 2048 * 256;
    bf16* dst = VT + (size_t)bh * 256 * 2048;
    __shared__ bf16 T[64][68];
    int s0 = blockIdx.x * 64, d0 = blockIdx.y * 64;
    int tid = threadIdx.x;
#pragma unroll
    for (int t = 0; t < 2; ++t) {
        int idx = tid + t * 256;
        int row = idx >> 3, c8 = (idx & 7) * 8;
        uint4 v = *(const uint4*)(src + (s0 + row) * 256 + d0 + c8);
        *(uint2*)&T[row][c8] = make_uint2(v.x, v.y);
        *(uint2*)&T[row][c8 + 4] = make_uint2(v.z, v.w);
    }
    __syncthreads();
#pragma unroll
    for (int t = 0; t < 2; ++t) {
        int idx = tid + t * 256;
        int crow = idx >> 3, r8 = (idx & 7) * 8;
        union { bf16 h[8]; uint4 u; } p;
#pragma unroll
        for (int j = 0; j < 8; ++j) p.h[j] = T[r8 + j][crow];
        *(uint4*)(dst + (d0 + crow) * 2048 + s0 + r8) = p.u;
    }
}

__global__ void lam_kernel(const float* __restrict__ lq1, const float* __restrict__ lk1,
                           const float* __restrict__ lq2, const float* __restrict__ lk2,
                           const float* __restrict__ lam_init, float* __restrict__ lam_out) {
    int tid = threadIdx.x; int hh = tid >> 4, i = tid & 15;
    float s1 = 0.f, s2 = 0.f;
#pragma unroll
    for (int j = 0; j < 16; ++j) {
        int d = i + j * 16;
        s1 += lq1[hh * 256 + d] * lk1[hh * 256 + d];
        s2 += lq2[hh * 256 + d] * lk2[hh * 256 + d];
    }
#pragma unroll
    for (int msk = 1; msk < 16; msk <<= 1) { s1 += __shfl_xor(s1, msk); s2 += __shfl_xor(s2, msk); }
    if (i == 0) lam_out[hh] = __expf(s1) - __expf(s2) + lam_init[hh];
}

// ---------------------------------------------------------------- projection GEMM
__global__ __launch_bounds__(256) void proj_gemm(
    const bf16* __restrict__ xb, const bf16* __restrict__ eb,
    const bf16* __restrict__ WTq, const bf16* __restrict__ WTk, const bf16* __restrict__ WTv,
    const float* __restrict__ bq, const float* __restrict__ bk, const float* __restrict__ bv,
    bf16* __restrict__ Qb, bf16* __restrict__ Kb, bf16* __restrict__ Vb) {
    int z = blockIdx.z;
    const bf16* A = (z == 0) ? xb : eb;
    const bf16* BT = (z == 0) ? WTq : (z == 1) ? WTk : WTv;
    const float* bias = (z == 0) ? bq : (z == 1) ? bk : bv;
    bf16* out = (z == 0) ? Qb : (z == 1) ? Kb : Vb;
    float qs = (z == 0) ? QK_PRESCALE : 1.0f;

    __shared__ alignas(16) bf16 As[128 * 32];
    __shared__ alignas(16) bf16 Bs[128 * 32];
    int m0 = blockIdx.x * 128, n0 = blockIdx.y * 128;
    int tid = threadIdx.x, w = tid >> 6, lane = tid & 63;
    int lrow = lane & 15, lgrp = lane >> 4, lk8 = lgrp * 8;
    int wr = (w >> 1) * 64, wc = (w & 1) * 64;

    f32x4 acc[4][4];
#pragma unroll
    for (int i = 0; i < 4; ++i)
#pragma unroll
        for (int j = 0; j < 4; ++j) acc[i][j] = (f32x4){0.f, 0.f, 0.f, 0.f};

    for (int k0 = 0; k0 < 256; k0 += 32) {
        __syncthreads();
#pragma unroll
        for (int t = 0; t < 2; ++t) {
            int c = tid + t * 256;
            int row = c >> 2, k8 = (c & 3) * 8;
            load_lds16(A + (m0 + row) * 256 + k0 + k8, &As[c * 8]);
            load_lds16(BT + (n0 + row) * 256 + k0 + k8, &Bs[c * 8]);
        }
        __syncthreads();
        bf16x8 af[4], bfr[4];
#pragma unroll
        for (int f = 0; f < 4; ++f) af[f] = *(const bf16x8*)&As[(wr + f * 16 + lrow) * 32 + lk8];
#pragma unroll
        for (int f = 0; f < 4; ++f) bfr[f] = *(const bf16x8*)&Bs[(wc + f * 16 + lrow) * 32 + lk8];
#pragma unroll
        for (int i = 0; i < 4; ++i)
#pragma unroll
            for (int j = 0; j < 4; ++j) acc[i][j] = MFMA16(af[i], bfr[j], acc[i][j]);
    }
#pragma unroll
    for (int i = 0; i < 4; ++i) {
#pragma unroll
        for (int j = 0; j < 4; ++j) {
            int n = n0 + wc + j * 16 + lrow;
            float bvv = bias[n];
            int hh = n >> 8, d = n & 255;
#pragma unroll
            for (int r = 0; r < 4; ++r) {
                int m = m0 + wr + i * 16 + lgrp * 4 + r;
                int bb = m >> 11, tt = m & 2047;
                out[(((size_t)bb * 16 + hh) * 2048 + tt) * 256 + d] = (bf16)((acc[i][j][r] + bvv) * qs);
            }
        }
    }
}

// ---------------------------------------------------------------- attention
// Branch-split waves, 32x32x16 MFMA, swapped operands (lane-local softmax).
// NO online max: scores are bounded; fixed offset M0=16 folded into QK acc init.
// p = exp2(s' - 16); all normalization cancels via 1/lsum in the epilogue.
__global__ __launch_bounds__(256, 2) void attn_kernel(
    const bf16* __restrict__ Qb, const bf16* __restrict__ Kb, const bf16* __restrict__ VTb,
    const float* __restrict__ lam_ws, const float* __restrict__ g, bf16* __restrict__ On) {
    __shared__ alignas(16) char SMEM[75264];
    bf16* KsB = (bf16*)SMEM;                  // [2][32*256]  (main loop)
    bf16* VsB = (bf16*)(SMEM + 32768);        // [2][256*32]  (main loop)
    float* o2buf  = (float*)SMEM;             // [64][256]    (epilogue, overlays K/V)
    float* smem_i = (float*)(SMEM + 65536);   // [128] 1/l1 | lam/l2
    float* smem_r = (float*)(SMEM + 66048);   // [64] rinv
    float* psum   = (float*)(SMEM + 66560);   // [64][33]

    int orig = blockIdx.x;
    int xcd = orig & 7, idx = orig >> 3;
    int bh = xcd * 4 + (idx >> 5);
    int qb = idx & 31;
    int b = bh >> 4, h = bh & 15;
    int q0 = qb * 64;

    int tid = threadIdx.x, w = tid >> 6, lane = tid & 63;
    int lq = lane & 31, hi = lane >> 5;
    int br = w >> 1, qw = (w & 1) * 32;
    int ksw = lq & 7;
    int vsw = (lq >> 1) & 3;
    bool hib = (hi != 0);

    const bf16* Qg = Qb + ((size_t)bh * 2048 + q0 + qw + lq) * 256 + br * 128;
    bf16x8 qf[8];
#pragma unroll
    for (int dk = 0; dk < 8; ++dk)
        qf[dk] = *(const bf16x8*)(Qg + dk * 16 + hi * 8);

    f32x16 o[8];
#pragma unroll
    for (int dt = 0; dt < 8; ++dt)
#pragma unroll
        for (int i = 0; i < 16; ++i) o[dt][i] = 0.f;
    float lsum = 0.f;

    const bf16* Kg = Kb + (size_t)bh * 2048 * 256;
    const bf16* VTg = VTb + (size_t)bh * 256 * 2048;

    auto STAGE = [&](int buf, int kt) {
        int s0 = kt * 32;
#pragma unroll
        for (int i = 0; i < 4; ++i) {
            int s = i * 256 + tid;
            int row = s >> 5;
            int cg = (s & 31) ^ (row & 7);
            load_lds16(Kg + (size_t)(s0 + row) * 256 + cg * 8, KsB + buf * 8192 + s * 8);
        }
#pragma unroll
        for (int i = 0; i < 4; ++i) {
            int s = i * 256 + tid;
            int row = s >> 2;
            int cg = (s & 3) ^ ((row >> 1) & 3);
            load_lds16(VTg + (size_t)row * 2048 + s0 + cg * 8, VsB + buf * 8192 + s * 8);
        }
    };

    STAGE(0, 0);
    __syncthreads();

    int cur = 0;
    for (int kt = 0; kt < 64; ++kt) {
        if (kt + 1 < 64) STAGE(cur ^ 1, kt + 1);
        const bf16* Kbuf = KsB + cur * 8192;
        const bf16* Vbuf = VsB + cur * 8192;

        // ---- QK^T: S[key][q] (A = K rows, B = Q rows); 2-way ILP.
        // sa carries the fixed -16 softmax offset as C-in (free).
        f32x16 sa, sb;
#pragma unroll
        for (int i = 0; i < 16; ++i) { sa[i] = M0_BIAS; sb[i] = 0.f; }
        __builtin_amdgcn_s_setprio(1);
#pragma unroll
        for (int dk = 0; dk < 4; ++dk) {
            bf16x8 k0 = *(const bf16x8*)&Kbuf[lq * 256 + (((br * 16 + 4 * dk + hi) ^ ksw) << 3)];
            bf16x8 k1 = *(const bf16x8*)&Kbuf[lq * 256 + (((br * 16 + 4 * dk + 2 + hi) ^ ksw) << 3)];
            sa = MFMA32(k0, qf[2 * dk], sa);
            sb = MFMA32(k1, qf[2 * dk + 1], sb);
        }
        __builtin_amdgcn_s_setprio(0);

        // ---- fixed-offset softmax: p = exp2(sa+sb), pure per-lane accumulate
        float p[16];
        float ls0 = 0.f, ls1 = 0.f;
#pragma unroll
        for (int i = 0; i < 8; ++i) { p[i] = exp2f(sa[i] + sb[i]); ls0 += p[i]; }
#pragma unroll
        for (int i = 8; i < 16; ++i) { p[i] = exp2f(sa[i] + sb[i]); ls1 += p[i]; }
        lsum += ls0 + ls1;

        // ---- pack P into PV A-fragments (portable cross-half exchange)
        u32 X0 = pk2(p[0], p[1]),   X1 = pk2(p[2], p[3]);
        u32 Y0 = pk2(p[4], p[5]),   Y1 = pk2(p[6], p[7]);
        u32 Z0 = pk2(p[8], p[9]),   Z1 = pk2(p[10], p[11]);
        u32 W0 = pk2(p[12], p[13]), W1 = pk2(p[14], p[15]);
        u32 pX0 = xswap(X0), pX1 = xswap(X1);
        u32 pY0 = xswap(Y0), pY1 = xswap(Y1);
        u32 pZ0 = xswap(Z0), pZ1 = xswap(Z1);
        u32 pW0 = xswap(W0), pW1 = xswap(W1);
        union { u32 u[4]; bf16x8 v; } PA0, PA1;
        PA0.u[0] = hib ? pY0 : X0;  PA0.u[1] = hib ? pY1 : X1;
        PA0.u[2] = hib ? Y0 : pX0;  PA0.u[3] = hib ? Y1 : pX1;
        PA1.u[0] = hib ? pW0 : Z0;  PA1.u[1] = hib ? pW1 : Z1;
        PA1.u[2] = hib ? W0 : pZ0;  PA1.u[3] = hib ? W1 : pZ1;

        // ---- PV: O[q][d] += P . V  (B = VT rows; 8 independent dt chains)
        __builtin_amdgcn_s_setprio(1);
#pragma unroll
        for (int dt = 0; dt < 8; ++dt) {
            const bf16* vrow = &Vbuf[(dt * 32 + lq) * 32];
            bf16x8 v0 = *(const bf16x8*)&vrow[(hi ^ vsw) << 3];
            o[dt] = MFMA32(PA0.v, v0, o[dt]);
            bf16x8 v1 = *(const bf16x8*)&vrow[((2 + hi) ^ vsw) << 3];
            o[dt] = MFMA32(PA1.v, v1, o[dt]);
        }
        __builtin_amdgcn_s_setprio(0);

        __syncthreads();
        cur ^= 1;
    }

    // ---- epilogue: combine partner l, cross-wave branch combine, RMS, store
    lsum += __shfl_xor(lsum, 32);
    float lam = lam_ws[h];
    float inv = (br == 0) ? 1.f / lsum : lam / lsum;
    smem_i[br * 64 + qw + lq] = inv;
    __syncthreads();

    if (br == 1) {
#pragma unroll
        for (int r = 0; r < 16; ++r) {
            int qp = (r & 3) + 8 * (r >> 2) + 4 * hi + qw;
            float i2 = smem_i[64 + qp];
#pragma unroll
            for (int dt = 0; dt < 8; ++dt)
                o2buf[qp * 256 + dt * 32 + lq] = o[dt][r] * i2;
        }
    }
    __syncthreads();

    if (br == 0) {
#pragma unroll
        for (int r = 0; r < 16; ++r) {
            int qp = (r & 3) + 8 * (r >> 2) + 4 * hi + qw;
            float i1 = smem_i[qp];
            float ss = 0.f;
#pragma unroll
            for (int dt = 0; dt < 8; ++dt) {
                float v = o[dt][r] * i1 - o2buf[qp * 256 + dt * 32 + lq];
                o[dt][r] = v;
                ss += v * v;
            }
            psum[qp * 33 + lq] = ss;
        }
    }
    __syncthreads();

    if (tid < 64) {
        float s = 0.f;
#pragma unroll
        for (int i = 0; i < 32; ++i) s += psum[tid * 33 + i];
        smem_r[tid] = 1.f / sqrtf(s * (1.f / 256.f) + RMS_EPS);
    }
    __syncthreads();

    if (br == 0) {
        float gv[8];
#pragma unroll
        for (int dt = 0; dt < 8; ++dt) gv[dt] = g[h * 256 + dt * 32 + lq] * OUT_SCALE;
#pragma unroll
        for (int r = 0; r < 16; ++r) {
            int qp = (r & 3) + 8 * (r >> 2) + 4 * hi + qw;
            float rv = smem_r[qp];
            size_t base = ((size_t)b * 2048 + q0 + qp) * 4096 + h * 256;
#pragma unroll
            for (int dt = 0; dt < 8; ++dt)
                On[base + dt * 32 + lq] = (bf16)(o[dt][r] * rv * gv[dt]);
        }
    }
}

// ---------------------------------------------------------------- output GEMM
__global__ __launch_bounds__(256) void out_gemm(const bf16* __restrict__ A, const bf16* __restrict__ BT,
                                                const float* __restrict__ bo, float* __restrict__ out) {
    __shared__ alignas(16) bf16 As[64 * 32];
    __shared__ alignas(16) bf16 Bs[64 * 32];
    int m0 = blockIdx.x * 64, n0 = blockIdx.y * 64;
    int tid = threadIdx.x, w = tid >> 6, lane = tid & 63;
    int lrow = lane & 15, lgrp = lane >> 4, lk8 = lgrp * 8;
    int wr = (w >> 1) * 32, wc = (w & 1) * 32;
    f32x4 acc[2][2];
#pragma unroll
    for (int i = 0; i < 2; ++i)
#pragma unroll
        for (int j = 0; j < 2; ++j) acc[i][j] = (f32x4){0.f, 0.f, 0.f, 0.f};
    for (int k0 = 0; k0 < 4096; k0 += 32) {
        __syncthreads();
        int row = tid >> 2, k8 = (tid & 3) * 8;
        load_lds16(A + (size_t)(m0 + row) * 4096 + k0 + k8, &As[tid * 8]);
        load_lds16(BT + (size_t)(n0 + row) * 4096 + k0 + k8, &Bs[tid * 8]);
        __syncthreads();
        bf16x8 af[2], bfr[2];
#pragma unroll
        for (int f = 0; f < 2; ++f) {
            af[f] = *(const bf16x8*)&As[(wr + f * 16 + lrow) * 32 + lk8];
            bfr[f] = *(const bf16x8*)&Bs[(wc + f * 16 + lrow) * 32 + lk8];
        }
#pragma unroll
        for (int i = 0; i < 2; ++i)
#pragma unroll
            for (int j = 0; j < 2; ++j) acc[i][j] = MFMA16(af[i], bfr[j], acc[i][j]);
    }
#pragma unroll
    for (int i = 0; i < 2; ++i)
#pragma unroll
        for (int j = 0; j < 2; ++j) {
            int n = n0 + wc + j * 16 + lrow;
            float bv = bo[n];
#pragma unroll
            for (int r = 0; r < 4; ++r) {
                int m = m0 + wr + i * 16 + lgrp * 4 + r;
                out[(size_t)m * 256 + n] = acc[i][j][r] + bv;
            }
        }
}

// ---------------------------------------------------------------- launch
extern "C" void kernel_launch(void* const* d_in, const int* in_sizes, int n_in,
                              void* d_out, int out_size, void* d_ws, size_t ws_size,
                              hipStream_t stream) {
    const float* x = (const float*)d_in[0];
    const float* enc = (const float*)d_in[1];
    const float* Wq = (const float*)d_in[2];
    const float* bq = (const float*)d_in[3];
    const float* Wk = (const float*)d_in[4];
    const float* bk = (const float*)d_in[5];
    const float* Wv = (const float*)d_in[6];
    const float* bv = (const float*)d_in[7];
    const float* lq1 = (const float*)d_in[8];
    const float* lk1 = (const float*)d_in[9];
    const float* lq2 = (const float*)d_in[10];
    const float* lk2 = (const float*)d_in[11];
    const float* lam_init = (const float*)d_in[12];
    const float* g = (const float*)d_in[13];
    const float* Wo = (const float*)d_in[14];
    const float* bo = (const float*)d_in[15];
    float* out = (float*)d_out;

    char* ws = (char*)d_ws;
    const size_t MB = 1024 * 1024;
    bf16* xb  = (bf16*)(ws + 0 * MB);
    bf16* eb  = (bf16*)(ws + 2 * MB);
    bf16* WTq = (bf16*)(ws + 4 * MB);
    bf16* WTk = (bf16*)(ws + 6 * MB);
    bf16* WTv = (bf16*)(ws + 8 * MB);
    bf16* WoT = (bf16*)(ws + 10 * MB);
    float* lam = (float*)(ws + 12 * MB);
    bf16* Qb  = (bf16*)(ws + 13 * MB);
    bf16* Kb  = (bf16*)(ws + 45 * MB);
    bf16* Vb  = (bf16*)(ws + 77 * MB);
    bf16* VTb = (bf16*)(ws + 109 * MB);
    bf16* On  = Vb;   // Vb dead after txp_v -> reuse

    hipLaunchKernelGGL(cvt_act, dim3(1024), dim3(256), 0, stream, x, enc, xb, eb);
    hipLaunchKernelGGL(txp_w, dim3(4, 4, 48), dim3(256), 0, stream, Wq, Wk, Wv, WTq, WTk, WTv);
    hipLaunchKernelGGL(txp_wo, dim3(4, 64, 1), dim3(256), 0, stream, Wo, WoT);
    hipLaunchKernelGGL(lam_kernel, dim3(1), dim3(256), 0, stream, lq1, lk1, lq2, lk2, lam_init, lam);
    hipLaunchKernelGGL(proj_gemm, dim3(32, 32, 3), dim3(256), 0, stream,
                       xb, eb, WTq, WTk, WTv, bq, bk, bv, Qb, Kb, Vb);
    hipLaunchKernelGGL(txp_v, dim3(32, 4, 32), dim3(256), 0, stream, Vb, VTb);
    hipLaunchKernelGGL(attn_kernel, dim3(1024), dim3(256), 0, stream, Qb, Kb, VTb, lam, g, On);
    hipLaunchKernelGGL(out_gemm, dim3(64, 4), dim3(256), 0, stream, On, WoT, bo, out);
}